// Round 1
// baseline (796.087 us; speedup 1.0000x reference)
//
#include <hip/hip_runtime.h>
#include <hip/hip_bf16.h>

#define N_NODES 100000
#define N_EDGES 1600000
#define N_FEAT 7
#define HID 128
#define N_CLASS 5
#define N_GRAPHS 8
#define NPB 16  // nodes per block in fused hidden-layer kernel (100000 % 16 == 0 via grid 6250)
#define SCAN_NBLK ((N_NODES + 1023) / 1024)   // 98

typedef __hip_bfloat16 bf16;

// ---------------- CSR build (dst-sorted adjacency) ----------------

__global__ void hist_kernel(const int* __restrict__ dst, int* __restrict__ deg) {
    int e = blockIdx.x * blockDim.x + threadIdx.x;
    if (e < N_EDGES) atomicAdd(&deg[dst[e]], 1);
}

__global__ __launch_bounds__(1024) void scan_phase1(const int* __restrict__ deg,
                                                    int* __restrict__ tmp,
                                                    int* __restrict__ bsum) {
    __shared__ int s[1024];
    int tid = threadIdx.x;
    int i = blockIdx.x * 1024 + tid;
    int v = (i < N_NODES) ? deg[i] : 0;
    s[tid] = v;
    __syncthreads();
    for (int off = 1; off < 1024; off <<= 1) {
        int u = (tid >= off) ? s[tid - off] : 0;
        __syncthreads();
        s[tid] += u;
        __syncthreads();
    }
    if (i < N_NODES) tmp[i] = s[tid] - v;            // exclusive
    if (tid == 1023) bsum[blockIdx.x] = s[1023];
}

__global__ __launch_bounds__(128) void scan_phase2(int* __restrict__ bsum) {
    __shared__ int s[128];
    int tid = threadIdx.x;
    int v = (tid < SCAN_NBLK) ? bsum[tid] : 0;
    s[tid] = v;
    __syncthreads();
    for (int off = 1; off < 128; off <<= 1) {
        int u = (tid >= off) ? s[tid - off] : 0;
        __syncthreads();
        s[tid] += u;
        __syncthreads();
    }
    if (tid < SCAN_NBLK) bsum[tid] = s[tid] - v;
}

__global__ __launch_bounds__(1024) void scan_phase3(const int* __restrict__ tmp,
                                                    const int* __restrict__ bsum,
                                                    int* __restrict__ rowptr,
                                                    int* __restrict__ cursor) {
    int i = blockIdx.x * 1024 + threadIdx.x;
    if (i < N_NODES) {
        int r = tmp[i] + bsum[blockIdx.x];
        rowptr[i] = r;
        cursor[i] = r;
    }
    if (i == 0) rowptr[N_NODES] = N_EDGES;
}

__global__ void scatter_kernel(const int* __restrict__ src, const int* __restrict__ dst,
                               const float* __restrict__ ea, int* __restrict__ cursor,
                               int2* __restrict__ csr) {
    int e = blockIdx.x * blockDim.x + threadIdx.x;
    if (e >= N_EDGES) return;
    int d = dst[e];
    int p = atomicAdd(&cursor[d], 1);
    csr[p] = make_int2(src[e], __float_as_int(ea[e]));
}

// ---------------- Layer 1 (in=7) ----------------
// 4 nodes per wave, 16 lanes per node. avg degree ~16 -> ~full lane utilization
// (previous version: 1 node per 64-lane wave -> ~75% lanes idle).

__global__ __launch_bounds__(64) void agg_l1(const float* __restrict__ x,
                                             const int2* __restrict__ csr,
                                             const int* __restrict__ rowptr,
                                             const float* __restrict__ We,
                                             const float* __restrict__ be,
                                             float* __restrict__ agg) {
    int lane = threadIdx.x;
    int sub = lane >> 4;          // node within wave: 0..3
    int l = lane & 15;            // lane within node group
    int n = blockIdx.x * 4 + sub; // grid = 25000 -> exact coverage
    float we[N_FEAT], bee[N_FEAT], p[N_FEAT];
#pragma unroll
    for (int k = 0; k < N_FEAT; ++k) { we[k] = We[k]; bee[k] = be[k]; p[k] = 0.f; }
    int r0 = rowptr[n], r1 = rowptr[n + 1];
    for (int i = r0 + l; i < r1; i += 16) {
        int2 sa = csr[i];
        int s = sa.x;
        float a = __int_as_float(sa.y);
#pragma unroll
        for (int k = 0; k < N_FEAT; ++k) {
            float m = x[s * N_FEAT + k] + a * we[k] + bee[k];
            p[k] += m > 0.f ? m : 0.f;
        }
    }
#pragma unroll
    for (int off = 8; off >= 1; off >>= 1)
#pragma unroll
        for (int k = 0; k < N_FEAT; ++k)
            p[k] += __shfl_xor(p[k], off, 16);
    if (l == 0) {
#pragma unroll
        for (int k = 0; k < N_FEAT; ++k) agg[n * N_FEAT + k] = p[k];
    }
}

__global__ void node_l1(const float* __restrict__ x, const float* __restrict__ agg,
                        const float* __restrict__ W, const float* __restrict__ b,
                        bf16* __restrict__ h) {
    __shared__ float t[N_FEAT];
    int n = blockIdx.x;
    int j = threadIdx.x;
    if (j < N_FEAT) t[j] = agg[n * N_FEAT + j] + x[n * N_FEAT + j];
    __syncthreads();
    float acc = b[j];
#pragma unroll
    for (int k = 0; k < N_FEAT; ++k) acc += t[k] * W[k * HID + j];
    h[n * HID + j] = __float2bfloat16(acc > 0.f ? acc : 0.f);
}

// ---------------- Fused hidden layer: gather-aggregate + GEMV ----------------
// block = 128 threads (j = feature), owns NPB=16 consecutive nodes.
// NPB=16 (was 8): halves the number of blocks -> halves W read traffic from L2
// (W is re-read once per block: 64 KB x blocks) and doubles FMA:W-load ratio.
// Edge records read via wave-uniform addresses (scalar loads, no LDS staging).
// hout MUST differ from hin (other blocks gather hin rows concurrently).
__global__ __launch_bounds__(128) void hidden_layer(
        const bf16* __restrict__ hin, const int2* __restrict__ csr,
        const int* __restrict__ rowptr, const float* __restrict__ We,
        const float* __restrict__ be, const float* __restrict__ W,
        const float* __restrict__ b, bf16* __restrict__ hout) {
    __shared__ float t[NPB][HID];   // 8 KB
    int j = threadIdx.x;
    int n0 = blockIdx.x * NPB;
    float wej = We[j], bej = be[j];

    for (int m = 0; m < NPB; ++m) {
        int n = n0 + m;
        int r0 = rowptr[n], r1 = rowptr[n + 1];
        float acc = 0.f;
#pragma unroll 4
        for (int i = r0; i < r1; ++i) {
            int2 sa = csr[i];               // uniform across block -> scalar load
            int s = sa.x;
            float a = __int_as_float(sa.y);
            float mm = __bfloat162float(hin[(size_t)s * HID + j]) + a * wej + bej;
            acc += mm > 0.f ? mm : 0.f;
        }
        t[m][j] = acc + __bfloat162float(hin[(size_t)n * HID + j]);
    }
    __syncthreads();

    float out[NPB];
#pragma unroll
    for (int m = 0; m < NPB; ++m) out[m] = b[j];
#pragma unroll 4
    for (int k = 0; k < HID; ++k) {
        float w = W[k * HID + j];
#pragma unroll
        for (int m = 0; m < NPB; ++m) out[m] += t[m][k] * w;
    }
#pragma unroll
    for (int m = 0; m < NPB; ++m) {
        float v = out[m];
        hout[(size_t)(n0 + m) * HID + j] = __float2bfloat16(v > 0.f ? v : 0.f);
    }
}

// ---------------- Pooling + head ----------------

__global__ void pool_kernel(const bf16* __restrict__ h, const int* __restrict__ batch,
                            float* __restrict__ pool, float* __restrict__ cnt) {
    int n0 = blockIdx.x * 64;
    int j = threadIdx.x;
    int nend = n0 + 64;
    if (nend > N_NODES) nend = N_NODES;
    if (n0 >= N_NODES) return;
    float sum = 0.f;
    int curg = batch[n0];
    int runstart = n0;
    for (int n = n0; n < nend; ++n) {
        int g = batch[n];
        if (g != curg) {
            atomicAdd(&pool[curg * HID + j], sum);
            if (j == 0) atomicAdd(&cnt[curg], (float)(n - runstart));
            sum = 0.f;
            curg = g;
            runstart = n;
        }
        sum += __bfloat162float(h[(size_t)n * HID + j]);
    }
    atomicAdd(&pool[curg * HID + j], sum);
    if (j == 0) atomicAdd(&cnt[curg], (float)(nend - runstart));
}

__global__ void final_kernel(const float* __restrict__ pool, const float* __restrict__ cnt,
                             const float* __restrict__ Wlin, const float* __restrict__ blin,
                             float* __restrict__ out) {
    int idx = threadIdx.x;
    if (idx >= N_GRAPHS * N_CLASS) return;
    int g = idx / N_CLASS, c = idx % N_CLASS;
    float invc = 1.f / fmaxf(cnt[g], 1.f);
    float acc = blin[c];
    for (int j = 0; j < HID; ++j) acc += pool[g * HID + j] * invc * Wlin[j * N_CLASS + c];
    out[idx] = acc;
}

extern "C" void kernel_launch(void* const* d_in, const int* in_sizes, int n_in,
                              void* d_out, int out_size, void* d_ws, size_t ws_size,
                              hipStream_t stream) {
    const float* x    = (const float*)d_in[0];
    const int*   ei   = (const int*)d_in[1];
    const float* ea   = (const float*)d_in[2];
    const int*   batch= (const int*)d_in[3];
    const float* We1  = (const float*)d_in[4];
    const float* be1  = (const float*)d_in[5];
    const float* W1   = (const float*)d_in[6];
    const float* b1   = (const float*)d_in[7];
    const float* We2  = (const float*)d_in[8];
    const float* be2  = (const float*)d_in[9];
    const float* W2   = (const float*)d_in[10];
    const float* b2   = (const float*)d_in[11];
    const float* We3  = (const float*)d_in[12];
    const float* be3  = (const float*)d_in[13];
    const float* W3   = (const float*)d_in[14];
    const float* b3   = (const float*)d_in[15];
    const float* Wlin = (const float*)d_in[16];
    const float* blin = (const float*)d_in[17];

    const int* src = ei;
    const int* dst = ei + N_EDGES;

    // workspace layout (csr first: 8B-aligned at base)
    char* w = (char*)d_ws;
    int2*  csr    = (int2*)w;                    w += sizeof(int2) * (size_t)N_EDGES;
    bf16*  A      = (bf16*)w;                    w += sizeof(bf16) * (size_t)N_NODES * HID;
    bf16*  B      = (bf16*)w;                    w += sizeof(bf16) * (size_t)N_NODES * HID;
    float* agg1   = (float*)w;                   w += sizeof(float) * (size_t)N_NODES * N_FEAT;
    float* pool   = (float*)w;                   w += sizeof(float) * N_GRAPHS * HID;
    float* cnt    = (float*)w;                   w += sizeof(float) * N_GRAPHS;
    int*   rowptr = (int*)w;                     w += sizeof(int) * (N_NODES + 1);
    int*   cursor = (int*)w;                     w += sizeof(int) * N_NODES;
    int*   deg    = (int*)w;                     w += sizeof(int) * N_NODES;
    int*   stmp   = (int*)w;                     w += sizeof(int) * N_NODES;
    int*   bsum   = (int*)w;                     w += sizeof(int) * SCAN_NBLK;

    // ---- CSR build ----
    hipMemsetAsync(deg, 0, sizeof(int) * N_NODES, stream);
    hipMemsetAsync(pool, 0, sizeof(float) * (N_GRAPHS * HID + N_GRAPHS), stream);
    hist_kernel<<<(N_EDGES + 255) / 256, 256, 0, stream>>>(dst, deg);
    scan_phase1<<<SCAN_NBLK, 1024, 0, stream>>>(deg, stmp, bsum);
    scan_phase2<<<1, 128, 0, stream>>>(bsum);
    scan_phase3<<<SCAN_NBLK, 1024, 0, stream>>>(stmp, bsum, rowptr, cursor);
    scatter_kernel<<<(N_EDGES + 255) / 256, 256, 0, stream>>>(src, dst, ea, cursor, csr);

    // ---- Layer 1 ----
    agg_l1<<<N_NODES / 4, 64, 0, stream>>>(x, csr, rowptr, We1, be1, agg1);
    node_l1<<<N_NODES, HID, 0, stream>>>(x, agg1, W1, b1, A);            // A = h1 (bf16)

    // ---- Layer 2: A -> B ----
    hidden_layer<<<N_NODES / NPB, 128, 0, stream>>>(A, csr, rowptr, We2, be2, W2, b2, B);

    // ---- Layer 3: B -> A ----
    hidden_layer<<<N_NODES / NPB, 128, 0, stream>>>(B, csr, rowptr, We3, be3, W3, b3, A);

    // ---- Pool + head ----
    pool_kernel<<<(N_NODES + 63) / 64, HID, 0, stream>>>(A, batch, pool, cnt);
    final_kernel<<<1, 64, 0, stream>>>(pool, cnt, Wlin, blin, (float*)d_out);
}

// Round 2
// 664.984 us; speedup vs baseline: 1.1972x; 1.1972x over previous
//
#include <hip/hip_runtime.h>
#include <hip/hip_bf16.h>

#define N_NODES 100000
#define N_EDGES 1600000
#define N_FEAT 7
#define HID 128
#define N_CLASS 5
#define N_GRAPHS 8
#define NPB 16  // nodes per block in fused hidden-layer kernel (grid 6250, 4 waves x 4 nodes)
#define SCAN_NBLK ((N_NODES + 1023) / 1024)   // 98

typedef __hip_bfloat16 bf16;

// ---------------- CSR build (dst-sorted adjacency) ----------------

__global__ void hist_kernel(const int* __restrict__ dst, int* __restrict__ deg) {
    int e = blockIdx.x * blockDim.x + threadIdx.x;
    if (e < N_EDGES) atomicAdd(&deg[dst[e]], 1);
}

__global__ __launch_bounds__(1024) void scan_phase1(const int* __restrict__ deg,
                                                    int* __restrict__ tmp,
                                                    int* __restrict__ bsum) {
    __shared__ int s[1024];
    int tid = threadIdx.x;
    int i = blockIdx.x * 1024 + tid;
    int v = (i < N_NODES) ? deg[i] : 0;
    s[tid] = v;
    __syncthreads();
    for (int off = 1; off < 1024; off <<= 1) {
        int u = (tid >= off) ? s[tid - off] : 0;
        __syncthreads();
        s[tid] += u;
        __syncthreads();
    }
    if (i < N_NODES) tmp[i] = s[tid] - v;            // exclusive
    if (tid == 1023) bsum[blockIdx.x] = s[1023];
}

__global__ __launch_bounds__(128) void scan_phase2(int* __restrict__ bsum) {
    __shared__ int s[128];
    int tid = threadIdx.x;
    int v = (tid < SCAN_NBLK) ? bsum[tid] : 0;
    s[tid] = v;
    __syncthreads();
    for (int off = 1; off < 128; off <<= 1) {
        int u = (tid >= off) ? s[tid - off] : 0;
        __syncthreads();
        s[tid] += u;
        __syncthreads();
    }
    if (tid < SCAN_NBLK) bsum[tid] = s[tid] - v;
}

__global__ __launch_bounds__(1024) void scan_phase3(const int* __restrict__ tmp,
                                                    const int* __restrict__ bsum,
                                                    int* __restrict__ rowptr,
                                                    int* __restrict__ cursor) {
    int i = blockIdx.x * 1024 + threadIdx.x;
    if (i < N_NODES) {
        int r = tmp[i] + bsum[blockIdx.x];
        rowptr[i] = r;
        cursor[i] = r;
    }
    if (i == 0) rowptr[N_NODES] = N_EDGES;
}

__global__ void scatter_kernel(const int* __restrict__ src, const int* __restrict__ dst,
                               const float* __restrict__ ea, int* __restrict__ cursor,
                               int2* __restrict__ csr) {
    int e = blockIdx.x * blockDim.x + threadIdx.x;
    if (e >= N_EDGES) return;
    int d = dst[e];
    int p = atomicAdd(&cursor[d], 1);
    csr[p] = make_int2(src[e], __float_as_int(ea[e]));
}

// ---------------- Layer 1 (in=7) ----------------
// 4 nodes per wave, 16 lanes per node.

__global__ __launch_bounds__(64) void agg_l1(const float* __restrict__ x,
                                             const int2* __restrict__ csr,
                                             const int* __restrict__ rowptr,
                                             const float* __restrict__ We,
                                             const float* __restrict__ be,
                                             float* __restrict__ agg) {
    int lane = threadIdx.x;
    int sub = lane >> 4;          // node within wave: 0..3
    int l = lane & 15;            // lane within node group
    int n = blockIdx.x * 4 + sub; // grid = 25000 -> exact coverage
    float we[N_FEAT], bee[N_FEAT], p[N_FEAT];
#pragma unroll
    for (int k = 0; k < N_FEAT; ++k) { we[k] = We[k]; bee[k] = be[k]; p[k] = 0.f; }
    int r0 = rowptr[n], r1 = rowptr[n + 1];
    for (int i = r0 + l; i < r1; i += 16) {
        int2 sa = csr[i];
        int s = sa.x;
        float a = __int_as_float(sa.y);
#pragma unroll
        for (int k = 0; k < N_FEAT; ++k) {
            float m = x[s * N_FEAT + k] + a * we[k] + bee[k];
            p[k] += m > 0.f ? m : 0.f;
        }
    }
#pragma unroll
    for (int off = 8; off >= 1; off >>= 1)
#pragma unroll
        for (int k = 0; k < N_FEAT; ++k)
            p[k] += __shfl_xor(p[k], off, 16);
    if (l == 0) {
#pragma unroll
        for (int k = 0; k < N_FEAT; ++k) agg[n * N_FEAT + k] = p[k];
    }
}

__global__ void node_l1(const float* __restrict__ x, const float* __restrict__ agg,
                        const float* __restrict__ W, const float* __restrict__ b,
                        bf16* __restrict__ h) {
    __shared__ float t[N_FEAT];
    int n = blockIdx.x;
    int j = threadIdx.x;
    if (j < N_FEAT) t[j] = agg[n * N_FEAT + j] + x[n * N_FEAT + j];
    __syncthreads();
    float acc = b[j];
#pragma unroll
    for (int k = 0; k < N_FEAT; ++k) acc += t[k] * W[k * HID + j];
    h[n * HID + j] = __float2bfloat16(acc > 0.f ? acc : 0.f);
}

// ---------------- Fused hidden layer: gather-aggregate + GEMV ----------------
// v2: latency-oriented gather. Round-1 counters: VALUBusy 40%, HBM 12%, 0 bank
// conflicts -> dependent-load latency bound (1 edge in flight per 128-thr group).
// Now: 256 threads = 4 independent waves, each wave owns 4 nodes. A lane loads a
// uint4 (8 bf16 feats, 16 B), so 16 lanes cover one 256 B row -> 4 edges in
// flight per wave per iteration (x unroll 2). Edge-slot partials combined with
// 2 shfl_xor per node. hout MUST differ from hin.
__global__ __launch_bounds__(256) void hidden_layer(
        const bf16* __restrict__ hin, const int2* __restrict__ csr,
        const int* __restrict__ rowptr, const float* __restrict__ We,
        const float* __restrict__ be, const float* __restrict__ W,
        const float* __restrict__ b, bf16* __restrict__ hout) {
    __shared__ __align__(16) float t[NPB][HID];   // 8 KB
    int tid = threadIdx.x;
    int wave = tid >> 6;
    int lane = tid & 63;
    int el = lane >> 4;          // edge slot 0..3
    int fc = lane & 15;          // feature chunk: feats fc*8 .. fc*8+7
    int n0 = blockIdx.x * NPB;

    float we8[8], be8[8];
#pragma unroll
    for (int q = 0; q < 8; ++q) {
        we8[q] = We[fc * 8 + q];
        be8[q] = be[fc * 8 + q];
    }

    const uint4* hin4 = (const uint4*)hin;   // one 128-feat bf16 row = 16 uint4

    for (int loc = 0; loc < 4; ++loc) {
        int m = wave * 4 + loc;
        int n = n0 + m;
        int r0 = rowptr[n], r1 = rowptr[n + 1];
        float acc[8];
#pragma unroll
        for (int q = 0; q < 8; ++q) acc[q] = 0.f;
#pragma unroll 2
        for (int i = r0 + el; i < r1; i += 4) {
            int2 sa = csr[i];
            int s = sa.x;
            float a = __int_as_float(sa.y);
            uint4 rv = hin4[(size_t)s * 16 + fc];
#pragma unroll
            for (int p = 0; p < 4; ++p) {
                unsigned u = ((const unsigned*)&rv)[p];
                float f0 = __uint_as_float(u << 16);          // low bf16
                float f1 = __uint_as_float(u & 0xffff0000u);  // high bf16
                float m0 = f0 + a * we8[2 * p] + be8[2 * p];
                float m1 = f1 + a * we8[2 * p + 1] + be8[2 * p + 1];
                acc[2 * p]     += m0 > 0.f ? m0 : 0.f;
                acc[2 * p + 1] += m1 > 0.f ? m1 : 0.f;
            }
        }
        // combine the 4 edge slots (lanes l, l^16, l^32 share fc)
#pragma unroll
        for (int q = 0; q < 8; ++q) {
            acc[q] += __shfl_xor(acc[q], 16, 64);
            acc[q] += __shfl_xor(acc[q], 32, 64);
        }
        if (el == 0) {
            uint4 sv = hin4[(size_t)n * 16 + fc];
#pragma unroll
            for (int p = 0; p < 4; ++p) {
                unsigned u = ((const unsigned*)&sv)[p];
                t[m][fc * 8 + 2 * p]     = acc[2 * p]     + __uint_as_float(u << 16);
                t[m][fc * 8 + 2 * p + 1] = acc[2 * p + 1] + __uint_as_float(u & 0xffff0000u);
            }
        }
    }
    __syncthreads();

    // GEMV: out[n0+mg*8+mm][j] = relu(b[j] + sum_k t[mg*8+mm][k] * W[k][j])
    int j = tid & 127;
    int mg = tid >> 7;
    float out[8];
#pragma unroll
    for (int mm = 0; mm < 8; ++mm) out[mm] = b[j];
    for (int k4 = 0; k4 < HID / 4; ++k4) {
        float w0 = W[(k4 * 4 + 0) * HID + j];
        float w1 = W[(k4 * 4 + 1) * HID + j];
        float w2 = W[(k4 * 4 + 2) * HID + j];
        float w3 = W[(k4 * 4 + 3) * HID + j];
#pragma unroll
        for (int mm = 0; mm < 8; ++mm) {
            float4 tv = *(const float4*)&t[mg * 8 + mm][k4 * 4];   // broadcast, conflict-free
            out[mm] += tv.x * w0 + tv.y * w1 + tv.z * w2 + tv.w * w3;
        }
    }
#pragma unroll
    for (int mm = 0; mm < 8; ++mm) {
        float v = out[mm];
        hout[(size_t)(n0 + mg * 8 + mm) * HID + j] = __float2bfloat16(v > 0.f ? v : 0.f);
    }
}

// ---------------- Pooling + head ----------------

__global__ void pool_kernel(const bf16* __restrict__ h, const int* __restrict__ batch,
                            float* __restrict__ pool, float* __restrict__ cnt) {
    int n0 = blockIdx.x * 64;
    int j = threadIdx.x;
    int nend = n0 + 64;
    if (nend > N_NODES) nend = N_NODES;
    if (n0 >= N_NODES) return;
    float sum = 0.f;
    int curg = batch[n0];
    int runstart = n0;
    for (int n = n0; n < nend; ++n) {
        int g = batch[n];
        if (g != curg) {
            atomicAdd(&pool[curg * HID + j], sum);
            if (j == 0) atomicAdd(&cnt[curg], (float)(n - runstart));
            sum = 0.f;
            curg = g;
            runstart = n;
        }
        sum += __bfloat162float(h[(size_t)n * HID + j]);
    }
    atomicAdd(&pool[curg * HID + j], sum);
    if (j == 0) atomicAdd(&cnt[curg], (float)(nend - runstart));
}

__global__ void final_kernel(const float* __restrict__ pool, const float* __restrict__ cnt,
                             const float* __restrict__ Wlin, const float* __restrict__ blin,
                             float* __restrict__ out) {
    int idx = threadIdx.x;
    if (idx >= N_GRAPHS * N_CLASS) return;
    int g = idx / N_CLASS, c = idx % N_CLASS;
    float invc = 1.f / fmaxf(cnt[g], 1.f);
    float acc = blin[c];
    for (int j = 0; j < HID; ++j) acc += pool[g * HID + j] * invc * Wlin[j * N_CLASS + c];
    out[idx] = acc;
}

extern "C" void kernel_launch(void* const* d_in, const int* in_sizes, int n_in,
                              void* d_out, int out_size, void* d_ws, size_t ws_size,
                              hipStream_t stream) {
    const float* x    = (const float*)d_in[0];
    const int*   ei   = (const int*)d_in[1];
    const float* ea   = (const float*)d_in[2];
    const int*   batch= (const int*)d_in[3];
    const float* We1  = (const float*)d_in[4];
    const float* be1  = (const float*)d_in[5];
    const float* W1   = (const float*)d_in[6];
    const float* b1   = (const float*)d_in[7];
    const float* We2  = (const float*)d_in[8];
    const float* be2  = (const float*)d_in[9];
    const float* W2   = (const float*)d_in[10];
    const float* b2   = (const float*)d_in[11];
    const float* We3  = (const float*)d_in[12];
    const float* be3  = (const float*)d_in[13];
    const float* W3   = (const float*)d_in[14];
    const float* b3   = (const float*)d_in[15];
    const float* Wlin = (const float*)d_in[16];
    const float* blin = (const float*)d_in[17];

    const int* src = ei;
    const int* dst = ei + N_EDGES;

    // workspace layout (csr first: 8B-aligned at base; A/B 16B-aligned for uint4 loads)
    char* w = (char*)d_ws;
    int2*  csr    = (int2*)w;                    w += sizeof(int2) * (size_t)N_EDGES;
    bf16*  A      = (bf16*)w;                    w += sizeof(bf16) * (size_t)N_NODES * HID;
    bf16*  B      = (bf16*)w;                    w += sizeof(bf16) * (size_t)N_NODES * HID;
    float* agg1   = (float*)w;                   w += sizeof(float) * (size_t)N_NODES * N_FEAT;
    float* pool   = (float*)w;                   w += sizeof(float) * N_GRAPHS * HID;
    float* cnt    = (float*)w;                   w += sizeof(float) * N_GRAPHS;
    int*   rowptr = (int*)w;                     w += sizeof(int) * (N_NODES + 1);
    int*   cursor = (int*)w;                     w += sizeof(int) * N_NODES;
    int*   deg    = (int*)w;                     w += sizeof(int) * N_NODES;
    int*   stmp   = (int*)w;                     w += sizeof(int) * N_NODES;
    int*   bsum   = (int*)w;                     w += sizeof(int) * SCAN_NBLK;

    // ---- CSR build ----
    hipMemsetAsync(deg, 0, sizeof(int) * N_NODES, stream);
    hipMemsetAsync(pool, 0, sizeof(float) * (N_GRAPHS * HID + N_GRAPHS), stream);
    hist_kernel<<<(N_EDGES + 255) / 256, 256, 0, stream>>>(dst, deg);
    scan_phase1<<<SCAN_NBLK, 1024, 0, stream>>>(deg, stmp, bsum);
    scan_phase2<<<1, 128, 0, stream>>>(bsum);
    scan_phase3<<<SCAN_NBLK, 1024, 0, stream>>>(stmp, bsum, rowptr, cursor);
    scatter_kernel<<<(N_EDGES + 255) / 256, 256, 0, stream>>>(src, dst, ea, cursor, csr);

    // ---- Layer 1 ----
    agg_l1<<<N_NODES / 4, 64, 0, stream>>>(x, csr, rowptr, We1, be1, agg1);
    node_l1<<<N_NODES, HID, 0, stream>>>(x, agg1, W1, b1, A);            // A = h1 (bf16)

    // ---- Layer 2: A -> B ----
    hidden_layer<<<N_NODES / NPB, 256, 0, stream>>>(A, csr, rowptr, We2, be2, W2, b2, B);

    // ---- Layer 3: B -> A ----
    hidden_layer<<<N_NODES / NPB, 256, 0, stream>>>(B, csr, rowptr, We3, be3, W3, b3, A);

    // ---- Pool + head ----
    pool_kernel<<<(N_NODES + 63) / 64, HID, 0, stream>>>(A, batch, pool, cnt);
    final_kernel<<<1, 64, 0, stream>>>(pool, cnt, Wlin, blin, (float*)d_out);
}

// Round 5
// 525.920 us; speedup vs baseline: 1.5137x; 1.2644x over previous
//
#include <hip/hip_runtime.h>
#include <hip/hip_bf16.h>

#define N_NODES 100000
#define N_EDGES 1600000
#define N_FEAT 7
#define HID 128
#define N_CLASS 5
#define N_GRAPHS 8
#define NPB 16  // nodes per block in fused hidden-layer kernel (grid 6250, 4 waves x 4 nodes)
#define SCAN_NBLK ((N_NODES + 1023) / 1024)   // 98
#define TLP 136  // padded LDS row (bf16 elems): 272 B stride

typedef __hip_bfloat16 bf16;
typedef __attribute__((ext_vector_type(8))) short short8;   // 8 bf16 (4 VGPRs)
typedef __attribute__((ext_vector_type(4))) float f32x4;    // MFMA accumulator

// ---------------- CSR build (dst-sorted adjacency) ----------------

__global__ void hist_kernel(const int* __restrict__ dst, int* __restrict__ deg) {
    int e = blockIdx.x * blockDim.x + threadIdx.x;
    if (e < N_EDGES) atomicAdd(&deg[dst[e]], 1);
}

__global__ __launch_bounds__(1024) void scan_phase1(const int* __restrict__ deg,
                                                    int* __restrict__ tmp,
                                                    int* __restrict__ bsum) {
    __shared__ int s[1024];
    int tid = threadIdx.x;
    int i = blockIdx.x * 1024 + tid;
    int v = (i < N_NODES) ? deg[i] : 0;
    s[tid] = v;
    __syncthreads();
    for (int off = 1; off < 1024; off <<= 1) {
        int u = (tid >= off) ? s[tid - off] : 0;
        __syncthreads();
        s[tid] += u;
        __syncthreads();
    }
    if (i < N_NODES) tmp[i] = s[tid] - v;            // exclusive
    if (tid == 1023) bsum[blockIdx.x] = s[1023];
}

__global__ __launch_bounds__(128) void scan_phase2(int* __restrict__ bsum) {
    __shared__ int s[128];
    int tid = threadIdx.x;
    int v = (tid < SCAN_NBLK) ? bsum[tid] : 0;
    s[tid] = v;
    __syncthreads();
    for (int off = 1; off < 128; off <<= 1) {
        int u = (tid >= off) ? s[tid - off] : 0;
        __syncthreads();
        s[tid] += u;
        __syncthreads();
    }
    if (tid < SCAN_NBLK) bsum[tid] = s[tid] - v;
}

__global__ __launch_bounds__(1024) void scan_phase3(const int* __restrict__ tmp,
                                                    const int* __restrict__ bsum,
                                                    int* __restrict__ rowptr,
                                                    int* __restrict__ cursor) {
    int i = blockIdx.x * 1024 + threadIdx.x;
    if (i < N_NODES) {
        int r = tmp[i] + bsum[blockIdx.x];
        rowptr[i] = r;
        cursor[i] = r;
    }
    if (i == 0) rowptr[N_NODES] = N_EDGES;
}

__global__ void scatter_kernel(const int* __restrict__ src, const int* __restrict__ dst,
                               const float* __restrict__ ea, int* __restrict__ cursor,
                               int2* __restrict__ csr) {
    int e = blockIdx.x * blockDim.x + threadIdx.x;
    if (e >= N_EDGES) return;
    int d = dst[e];
    int p = atomicAdd(&cursor[d], 1);
    csr[p] = make_int2(src[e], __float_as_int(ea[e]));
}

// ---------------- W pre-pack into MFMA B-fragment order (bf16) ----------------
// B-frag for mfma_f32_16x16x32_bf16: lane l holds B[k=(l>>4)*8+q][col=l&15].
// Wp[((jt*4+kk)*64 + l)*8 + q] = bf16(W[kk*32 + (l>>4)*8 + q][jt*16 + (l&15)])

__global__ void pack_w(const float* __restrict__ W, bf16* __restrict__ Wp) {
    int t = blockIdx.x * blockDim.x + threadIdx.x;   // 0..2047
    if (t >= 2048) return;
    int l = t & 63;
    int kk = (t >> 6) & 3;
    int jt = t >> 8;
    int kbase = kk * 32 + (l >> 4) * 8;
    int j = jt * 16 + (l & 15);
#pragma unroll
    for (int q = 0; q < 8; ++q)
        Wp[t * 8 + q] = __float2bfloat16(W[(kbase + q) * HID + j]);
}

// ---------------- Layer 1 (in=7) ----------------
// 4 nodes per wave, 16 lanes per node.

__global__ __launch_bounds__(64) void agg_l1(const float* __restrict__ x,
                                             const int2* __restrict__ csr,
                                             const int* __restrict__ rowptr,
                                             const float* __restrict__ We,
                                             const float* __restrict__ be,
                                             float* __restrict__ agg) {
    int lane = threadIdx.x;
    int sub = lane >> 4;          // node within wave: 0..3
    int l = lane & 15;            // lane within node group
    int n = blockIdx.x * 4 + sub; // grid = 25000 -> exact coverage
    float we[N_FEAT], bee[N_FEAT], p[N_FEAT];
#pragma unroll
    for (int k = 0; k < N_FEAT; ++k) { we[k] = We[k]; bee[k] = be[k]; p[k] = 0.f; }
    int r0 = rowptr[n], r1 = rowptr[n + 1];
    for (int i = r0 + l; i < r1; i += 16) {
        int2 sa = csr[i];
        int s = sa.x;
        float a = __int_as_float(sa.y);
#pragma unroll
        for (int k = 0; k < N_FEAT; ++k) {
            float m = x[s * N_FEAT + k] + a * we[k] + bee[k];
            p[k] += m > 0.f ? m : 0.f;
        }
    }
#pragma unroll
    for (int off = 8; off >= 1; off >>= 1)
#pragma unroll
        for (int k = 0; k < N_FEAT; ++k)
            p[k] += __shfl_xor(p[k], off, 16);
    if (l == 0) {
#pragma unroll
        for (int k = 0; k < N_FEAT; ++k) agg[n * N_FEAT + k] = p[k];
    }
}

__global__ void node_l1(const float* __restrict__ x, const float* __restrict__ agg,
                        const float* __restrict__ W, const float* __restrict__ b,
                        bf16* __restrict__ h) {
    __shared__ float t[N_FEAT];
    int n = blockIdx.x;
    int j = threadIdx.x;
    if (j < N_FEAT) t[j] = agg[n * N_FEAT + j] + x[n * N_FEAT + j];
    __syncthreads();
    float acc = b[j];
#pragma unroll
    for (int k = 0; k < N_FEAT; ++k) acc += t[k] * W[k * HID + j];
    h[n * HID + j] = __float2bfloat16(acc > 0.f ? acc : 0.f);
}

// ---------------- Fused hidden layer: gather-aggregate + MFMA node-update ----------------
// v3: round-2 counters (VALUBusy 65%, HBM 17%, MfmaUtil 0) -> GEMV phase was
// ~half the kernel in scalar FMAs (~1024 FMA + 256 ds_read_b128 per wave).
// Replace with mfma_f32_16x16x32_bf16: per wave 2 j-tiles x 4 k-steps = 8 MFMA.
// Aggregated node vector t stored in LDS as bf16 [16][136].
// Verified fragment mapping (m89): A lane l: row=l&15, k=(l>>4)*8+q;
//                                  B lane l: col=l&15, k=(l>>4)*8+q;
//                                  D lane l: col=l&15, row=(l>>4)*4+reg.
// hout MUST differ from hin.
__global__ __launch_bounds__(256) void hidden_layer(
        const bf16* __restrict__ hin, const int2* __restrict__ csr,
        const int* __restrict__ rowptr, const float* __restrict__ We,
        const float* __restrict__ be, const bf16* __restrict__ Wp,
        const float* __restrict__ b, bf16* __restrict__ hout) {
    __shared__ __align__(16) unsigned short tl[NPB][TLP];   // bf16 bits, 4.3 KB
    int tid = threadIdx.x;
    int wave = tid >> 6;
    int lane = tid & 63;
    int el = lane >> 4;          // edge slot 0..3
    int fc = lane & 15;          // feature chunk: feats fc*8 .. fc*8+7
    int n0 = blockIdx.x * NPB;

    float we8[8], be8[8];
#pragma unroll
    for (int q = 0; q < 8; ++q) {
        we8[q] = We[fc * 8 + q];
        be8[q] = be[fc * 8 + q];
    }

    const uint4* hin4 = (const uint4*)hin;   // one 128-feat bf16 row = 16 uint4

    for (int loc = 0; loc < 4; ++loc) {
        int m = wave * 4 + loc;
        int n = n0 + m;
        int r0 = rowptr[n], r1 = rowptr[n + 1];
        float acc[8];
#pragma unroll
        for (int q = 0; q < 8; ++q) acc[q] = 0.f;
#pragma unroll 2
        for (int i = r0 + el; i < r1; i += 4) {
            int2 sa = csr[i];
            int s = sa.x;
            float a = __int_as_float(sa.y);
            uint4 rv = hin4[(size_t)s * 16 + fc];
#pragma unroll
            for (int p = 0; p < 4; ++p) {
                unsigned u = ((const unsigned*)&rv)[p];
                float f0 = __uint_as_float(u << 16);          // low bf16
                float f1 = __uint_as_float(u & 0xffff0000u);  // high bf16
                float m0 = f0 + a * we8[2 * p] + be8[2 * p];
                float m1 = f1 + a * we8[2 * p + 1] + be8[2 * p + 1];
                acc[2 * p]     += m0 > 0.f ? m0 : 0.f;
                acc[2 * p + 1] += m1 > 0.f ? m1 : 0.f;
            }
        }
        // combine the 4 edge slots (lanes l, l^16, l^32 share fc)
#pragma unroll
        for (int q = 0; q < 8; ++q) {
            acc[q] += __shfl_xor(acc[q], 16, 64);
            acc[q] += __shfl_xor(acc[q], 32, 64);
        }
        if (el == 0) {
            uint4 sv = hin4[(size_t)n * 16 + fc];
            unsigned short pk[8];
#pragma unroll
            for (int p = 0; p < 4; ++p) {
                unsigned u = ((const unsigned*)&sv)[p];
                float v0 = acc[2 * p]     + __uint_as_float(u << 16);
                float v1 = acc[2 * p + 1] + __uint_as_float(u & 0xffff0000u);
                bf16 h0 = __float2bfloat16(v0);
                bf16 h1 = __float2bfloat16(v1);
                pk[2 * p]     = *(unsigned short*)&h0;
                pk[2 * p + 1] = *(unsigned short*)&h1;
            }
            *(uint4*)&tl[m][fc * 8] = *(const uint4*)pk;   // one ds_write_b128, conflict-free
        }
    }
    __syncthreads();

    // MFMA node-update: out[m][j] = relu(b[j] + sum_k t[m][k] * W[k][j])
    // wave handles j-tiles jt0=2*wave, jt1=2*wave+1 (all 16 rows).
    int c = lane & 15;           // A row / D col
    int kq = lane >> 4;          // k-chunk selector
    int jt0 = wave * 2, jt1 = jt0 + 1;
    f32x4 d0 = {0.f, 0.f, 0.f, 0.f}, d1 = {0.f, 0.f, 0.f, 0.f};
    const short8* wp = (const short8*)Wp;
#pragma unroll
    for (int kk = 0; kk < 4; ++kk) {
        short8 a  = *(const short8*)&tl[c][kk * 32 + kq * 8];
        short8 b0 = wp[(jt0 * 4 + kk) * 64 + lane];
        short8 b1 = wp[(jt1 * 4 + kk) * 64 + lane];
        d0 = __builtin_amdgcn_mfma_f32_16x16x32_bf16(a, b0, d0, 0, 0, 0);
        d1 = __builtin_amdgcn_mfma_f32_16x16x32_bf16(a, b1, d1, 0, 0, 0);
    }
    float bv0 = b[jt0 * 16 + c];
    float bv1 = b[jt1 * 16 + c];
#pragma unroll
    for (int i = 0; i < 4; ++i) {
        int m = kq * 4 + i;
        size_t base = (size_t)(n0 + m) * HID;
        float v0 = d0[i] + bv0;
        float v1 = d1[i] + bv1;
        hout[base + jt0 * 16 + c] = __float2bfloat16(v0 > 0.f ? v0 : 0.f);
        hout[base + jt1 * 16 + c] = __float2bfloat16(v1 > 0.f ? v1 : 0.f);
    }
}

// ---------------- Pooling + head ----------------

__global__ void pool_kernel(const bf16* __restrict__ h, const int* __restrict__ batch,
                            float* __restrict__ pool, float* __restrict__ cnt) {
    int n0 = blockIdx.x * 64;
    int j = threadIdx.x;
    int nend = n0 + 64;
    if (nend > N_NODES) nend = N_NODES;
    if (n0 >= N_NODES) return;
    float sum = 0.f;
    int curg = batch[n0];
    int runstart = n0;
    for (int n = n0; n < nend; ++n) {
        int g = batch[n];
        if (g != curg) {
            atomicAdd(&pool[curg * HID + j], sum);
            if (j == 0) atomicAdd(&cnt[curg], (float)(n - runstart));
            sum = 0.f;
            curg = g;
            runstart = n;
        }
        sum += __bfloat162float(h[(size_t)n * HID + j]);
    }
    atomicAdd(&pool[curg * HID + j], sum);
    if (j == 0) atomicAdd(&cnt[curg], (float)(nend - runstart));
}

__global__ void final_kernel(const float* __restrict__ pool, const float* __restrict__ cnt,
                             const float* __restrict__ Wlin, const float* __restrict__ blin,
                             float* __restrict__ out) {
    int idx = threadIdx.x;
    if (idx >= N_GRAPHS * N_CLASS) return;
    int g = idx / N_CLASS, c = idx % N_CLASS;
    float invc = 1.f / fmaxf(cnt[g], 1.f);
    float acc = blin[c];
    for (int j = 0; j < HID; ++j) acc += pool[g * HID + j] * invc * Wlin[j * N_CLASS + c];
    out[idx] = acc;
}

extern "C" void kernel_launch(void* const* d_in, const int* in_sizes, int n_in,
                              void* d_out, int out_size, void* d_ws, size_t ws_size,
                              hipStream_t stream) {
    const float* x    = (const float*)d_in[0];
    const int*   ei   = (const int*)d_in[1];
    const float* ea   = (const float*)d_in[2];
    const int*   batch= (const int*)d_in[3];
    const float* We1  = (const float*)d_in[4];
    const float* be1  = (const float*)d_in[5];
    const float* W1   = (const float*)d_in[6];
    const float* b1   = (const float*)d_in[7];
    const float* We2  = (const float*)d_in[8];
    const float* be2  = (const float*)d_in[9];
    const float* W2   = (const float*)d_in[10];
    const float* b2   = (const float*)d_in[11];
    const float* We3  = (const float*)d_in[12];
    const float* be3  = (const float*)d_in[13];
    const float* W3   = (const float*)d_in[14];
    const float* b3   = (const float*)d_in[15];
    const float* Wlin = (const float*)d_in[16];
    const float* blin = (const float*)d_in[17];

    const int* src = ei;
    const int* dst = ei + N_EDGES;

    // workspace layout (csr first: 16B-aligned at base; Wp before A keeps 16B alignment)
    char* w = (char*)d_ws;
    int2*  csr    = (int2*)w;                    w += sizeof(int2) * (size_t)N_EDGES;   // 12.8 MB (16B mult)
    bf16*  Wp2    = (bf16*)w;                    w += sizeof(bf16) * 8 * 4 * 64 * 8;    // 32 KB
    bf16*  Wp3    = (bf16*)w;                    w += sizeof(bf16) * 8 * 4 * 64 * 8;    // 32 KB
    bf16*  A      = (bf16*)w;                    w += sizeof(bf16) * (size_t)N_NODES * HID;
    bf16*  B      = (bf16*)w;                    w += sizeof(bf16) * (size_t)N_NODES * HID;
    float* agg1   = (float*)w;                   w += sizeof(float) * (size_t)N_NODES * N_FEAT;
    float* pool   = (float*)w;                   w += sizeof(float) * N_GRAPHS * HID;
    float* cnt    = (float*)w;                   w += sizeof(float) * N_GRAPHS;
    int*   rowptr = (int*)w;                     w += sizeof(int) * (N_NODES + 1);
    int*   cursor = (int*)w;                     w += sizeof(int) * N_NODES;
    int*   deg    = (int*)w;                     w += sizeof(int) * N_NODES;
    int*   stmp   = (int*)w;                     w += sizeof(int) * N_NODES;
    int*   bsum   = (int*)w;                     w += sizeof(int) * SCAN_NBLK;

    // ---- CSR build + weight pack ----
    hipMemsetAsync(deg, 0, sizeof(int) * N_NODES, stream);
    hipMemsetAsync(pool, 0, sizeof(float) * (N_GRAPHS * HID + N_GRAPHS), stream);
    hist_kernel<<<(N_EDGES + 255) / 256, 256, 0, stream>>>(dst, deg);
    pack_w<<<8, 256, 0, stream>>>(W2, Wp2);
    pack_w<<<8, 256, 0, stream>>>(W3, Wp3);
    scan_phase1<<<SCAN_NBLK, 1024, 0, stream>>>(deg, stmp, bsum);
    scan_phase2<<<1, 128, 0, stream>>>(bsum);
    scan_phase3<<<SCAN_NBLK, 1024, 0, stream>>>(stmp, bsum, rowptr, cursor);
    scatter_kernel<<<(N_EDGES + 255) / 256, 256, 0, stream>>>(src, dst, ea, cursor, csr);

    // ---- Layer 1 ----
    agg_l1<<<N_NODES / 4, 64, 0, stream>>>(x, csr, rowptr, We1, be1, agg1);
    node_l1<<<N_NODES, HID, 0, stream>>>(x, agg1, W1, b1, A);            // A = h1 (bf16)

    // ---- Layer 2: A -> B ----
    hidden_layer<<<N_NODES / NPB, 256, 0, stream>>>(A, csr, rowptr, We2, be2, Wp2, b2, B);

    // ---- Layer 3: B -> A ----
    hidden_layer<<<N_NODES / NPB, 256, 0, stream>>>(B, csr, rowptr, We3, be3, Wp3, b3, A);

    // ---- Pool + head ----
    pool_kernel<<<(N_NODES + 63) / 64, HID, 0, stream>>>(A, batch, pool, cnt);
    final_kernel<<<1, 64, 0, stream>>>(pool, cnt, Wlin, blin, (float*)d_out);
}

// Round 7
// 496.237 us; speedup vs baseline: 1.6042x; 1.0598x over previous
//
#include <hip/hip_runtime.h>
#include <hip/hip_bf16.h>

#define N_NODES 100000
#define N_EDGES 1600000
#define N_FEAT 7
#define HID 128
#define N_CLASS 5
#define N_GRAPHS 8
#define NPB 16  // nodes per block in fused hidden-layer kernel (grid 6250, 4 waves x 4 nodes)
#define SCAN_NBLK ((N_NODES + 1023) / 1024)   // 98
#define TLP 136  // padded LDS row (bf16 elems): 272 B stride
#define NBKT 98        // ceil(N_NODES / 1024) dst-buckets for local scatter
#define BKT_SHIFT 10
#define TILE 4096      // edges per partition block
#define CPB 16         // chunks per bucket in scatter_local

typedef __hip_bfloat16 bf16;
typedef __attribute__((ext_vector_type(8))) short short8;   // 8 bf16 (4 VGPRs)
typedef __attribute__((ext_vector_type(4))) float f32x4;    // MFMA accumulator

// ---------------- CSR build (dst-sorted adjacency) ----------------

__global__ void hist_kernel(const int* __restrict__ dst, int* __restrict__ deg) {
    int e = blockIdx.x * blockDim.x + threadIdx.x;
    if (e < N_EDGES) atomicAdd(&deg[dst[e]], 1);
}

__global__ __launch_bounds__(1024) void scan_phase1(const int* __restrict__ deg,
                                                    int* __restrict__ tmp,
                                                    int* __restrict__ bsum) {
    __shared__ int s[1024];
    int tid = threadIdx.x;
    int i = blockIdx.x * 1024 + tid;
    int v = (i < N_NODES) ? deg[i] : 0;
    s[tid] = v;
    __syncthreads();
    for (int off = 1; off < 1024; off <<= 1) {
        int u = (tid >= off) ? s[tid - off] : 0;
        __syncthreads();
        s[tid] += u;
        __syncthreads();
    }
    if (i < N_NODES) tmp[i] = s[tid] - v;            // exclusive
    if (tid == 1023) bsum[blockIdx.x] = s[1023];
}

__global__ __launch_bounds__(128) void scan_phase2(int* __restrict__ bsum) {
    __shared__ int s[128];
    int tid = threadIdx.x;
    int v = (tid < SCAN_NBLK) ? bsum[tid] : 0;
    s[tid] = v;
    __syncthreads();
    for (int off = 1; off < 128; off <<= 1) {
        int u = (tid >= off) ? s[tid - off] : 0;
        __syncthreads();
        s[tid] += u;
        __syncthreads();
    }
    if (tid < SCAN_NBLK) bsum[tid] = s[tid] - v;
}

__global__ __launch_bounds__(1024) void scan_phase3(const int* __restrict__ tmp,
                                                    const int* __restrict__ bsum,
                                                    int* __restrict__ rowptr,
                                                    int* __restrict__ cursor,
                                                    int* __restrict__ bcur) {
    int i = blockIdx.x * 1024 + threadIdx.x;
    if (i < N_NODES) {
        int r = tmp[i] + bsum[blockIdx.x];
        rowptr[i] = r;
        cursor[i] = r;
        if ((i & 1023) == 0) bcur[i >> BKT_SHIFT] = r;   // bucket write cursors for partition
    }
    if (i == 0) rowptr[N_NODES] = N_EDGES;
}

// ---- Pass A: LDS counting-sort each edge tile by dst-bucket, write bucket-major ----
// Replaces random 8B global scatter (round-5 counters: WRITE_SIZE 100 MB for a
// 12.8 MB array = 8x line amplification from cross-XCD false sharing).
// Writes become ~42-edge coalesced runs per bucket per tile.
__global__ __launch_bounds__(256) void partition_kernel(
        const int* __restrict__ src, const int* __restrict__ dst,
        const float* __restrict__ ea, int* __restrict__ bcur,
        int2* __restrict__ tmp2, int* __restrict__ tmpd) {
    __shared__ int lsrc[TILE], lea[TILE], ldst[TILE];   // 48 KB
    __shared__ int cnt[NBKT], gbase[NBKT];
    __shared__ int off[128];
    int tid = threadIdx.x;
    int e0 = blockIdx.x * TILE;
    int nedge = N_EDGES - e0; if (nedge > TILE) nedge = TILE;

    for (int bkt = tid; bkt < NBKT; bkt += 256) cnt[bkt] = 0;
    __syncthreads();
    for (int t = tid; t < nedge; t += 256)
        atomicAdd(&cnt[dst[e0 + t] >> BKT_SHIFT], 1);
    __syncthreads();
    if (tid < 128) off[tid] = (tid < NBKT) ? cnt[tid] : 0;
    __syncthreads();
    for (int o = 1; o < 128; o <<= 1) {                  // Hillis-Steele inclusive scan
        int u = 0;
        if (tid < 128 && tid >= o) u = off[tid - o];
        __syncthreads();
        if (tid < 128) off[tid] += u;
        __syncthreads();
    }
    if (tid < NBKT) {
        off[tid] -= cnt[tid];                            // inclusive -> exclusive
        gbase[tid] = atomicAdd(&bcur[tid], cnt[tid]);    // reserve global bucket range
    }
    __syncthreads();
    if (tid < NBKT) cnt[tid] = 0;                        // reuse as rank counter
    __syncthreads();
    for (int t = tid; t < nedge; t += 256) {
        int d = dst[e0 + t];
        int bkt = d >> BKT_SHIFT;
        int sp = off[bkt] + atomicAdd(&cnt[bkt], 1);     // sorted slot in tile
        lsrc[sp] = src[e0 + t];
        lea[sp] = __float_as_int(ea[e0 + t]);
        ldst[sp] = d;
    }
    __syncthreads();
    for (int t = tid; t < nedge; t += 256) {             // bucket-grouped coalesced writeout
        int d = ldst[t];
        int bkt = d >> BKT_SHIFT;
        int gi = gbase[bkt] + (t - off[bkt]);
        tmp2[gi] = make_int2(lsrc[t], lea[t]);
        tmpd[gi] = d;
    }
}

// ---- Pass B: scatter within bucket. All chunks of a bucket on ONE XCD
// (blockIdx%8 heuristic, perf-only): csr write window ~131 KB + cursor window
// 4 KB stay in that XCD's L2 -> full-line merging, compulsory-only HBM writes.
__global__ __launch_bounds__(256) void scatter_local(
        const int2* __restrict__ tmp2, const int* __restrict__ tmpd,
        const int* __restrict__ rowptr, int* __restrict__ cursor,
        int2* __restrict__ csr) {
    int bid = blockIdx.x;
    int xcd = bid & 7;
    int grp = bid >> 3;
    int b = (grp / CPB) * 8 + xcd;       // bucket: all its chunks share blockIdx%8
    int c = grp % CPB;                    // chunk within bucket
    if (b >= NBKT) return;
    int r0 = rowptr[b << BKT_SHIFT];
    int nb1 = (b + 1) << BKT_SHIFT; if (nb1 > N_NODES) nb1 = N_NODES;
    int r1 = rowptr[nb1];
    int count = r1 - r0;
    int per = (count + CPB - 1) / CPB;
    int s = r0 + c * per;
    int e = s + per; if (e > r1) e = r1;
    for (int i = s + threadIdx.x; i < e; i += 256) {
        int d = tmpd[i];
        int p = atomicAdd(&cursor[d], 1);
        csr[p] = tmp2[i];
    }
}

// ---------------- W pre-pack into MFMA B-fragment order (bf16) ----------------
// B-frag for mfma_f32_16x16x32_bf16: lane l holds B[k=(l>>4)*8+q][col=l&15].
// Wp[((jt*4+kk)*64 + l)*8 + q] = bf16(W[kk*32 + (l>>4)*8 + q][jt*16 + (l&15)])

__global__ void pack_w(const float* __restrict__ W, bf16* __restrict__ Wp) {
    int t = blockIdx.x * blockDim.x + threadIdx.x;   // 0..2047
    if (t >= 2048) return;
    int l = t & 63;
    int kk = (t >> 6) & 3;
    int jt = t >> 8;
    int kbase = kk * 32 + (l >> 4) * 8;
    int j = jt * 16 + (l & 15);
#pragma unroll
    for (int q = 0; q < 8; ++q)
        Wp[t * 8 + q] = __float2bfloat16(W[(kbase + q) * HID + j]);
}

// ---------------- Layer 1 (in=7) ----------------
// 4 nodes per wave, 16 lanes per node.

__global__ __launch_bounds__(64) void agg_l1(const float* __restrict__ x,
                                             const int2* __restrict__ csr,
                                             const int* __restrict__ rowptr,
                                             const float* __restrict__ We,
                                             const float* __restrict__ be,
                                             float* __restrict__ agg) {
    int lane = threadIdx.x;
    int sub = lane >> 4;          // node within wave: 0..3
    int l = lane & 15;            // lane within node group
    int n = blockIdx.x * 4 + sub; // grid = 25000 -> exact coverage
    float we[N_FEAT], bee[N_FEAT], p[N_FEAT];
#pragma unroll
    for (int k = 0; k < N_FEAT; ++k) { we[k] = We[k]; bee[k] = be[k]; p[k] = 0.f; }
    int r0 = rowptr[n], r1 = rowptr[n + 1];
    for (int i = r0 + l; i < r1; i += 16) {
        int2 sa = csr[i];
        int s = sa.x;
        float a = __int_as_float(sa.y);
#pragma unroll
        for (int k = 0; k < N_FEAT; ++k) {
            float m = x[s * N_FEAT + k] + a * we[k] + bee[k];
            p[k] += m > 0.f ? m : 0.f;
        }
    }
#pragma unroll
    for (int off = 8; off >= 1; off >>= 1)
#pragma unroll
        for (int k = 0; k < N_FEAT; ++k)
            p[k] += __shfl_xor(p[k], off, 16);
    if (l == 0) {
#pragma unroll
        for (int k = 0; k < N_FEAT; ++k) agg[n * N_FEAT + k] = p[k];
    }
}

__global__ void node_l1(const float* __restrict__ x, const float* __restrict__ agg,
                        const float* __restrict__ W, const float* __restrict__ b,
                        bf16* __restrict__ h) {
    __shared__ float t[N_FEAT];
    int n = blockIdx.x;
    int j = threadIdx.x;
    if (j < N_FEAT) t[j] = agg[n * N_FEAT + j] + x[n * N_FEAT + j];
    __syncthreads();
    float acc = b[j];
#pragma unroll
    for (int k = 0; k < N_FEAT; ++k) acc += t[k] * W[k * HID + j];
    h[n * HID + j] = __float2bfloat16(acc > 0.f ? acc : 0.f);
}

// ---------------- Fused hidden layer: gather-aggregate + MFMA node-update ----------------
// Verified fragment mapping (m89): A lane l: row=l&15, k=(l>>4)*8+q;
//                                  B lane l: col=l&15, k=(l>>4)*8+q;
//                                  D lane l: col=l&15, row=(l>>4)*4+reg.
// hout MUST differ from hin.
__global__ __launch_bounds__(256) void hidden_layer(
        const bf16* __restrict__ hin, const int2* __restrict__ csr,
        const int* __restrict__ rowptr, const float* __restrict__ We,
        const float* __restrict__ be, const bf16* __restrict__ Wp,
        const float* __restrict__ b, bf16* __restrict__ hout) {
    __shared__ __align__(16) unsigned short tl[NPB][TLP];   // bf16 bits, 4.3 KB
    int tid = threadIdx.x;
    int wave = tid >> 6;
    int lane = tid & 63;
    int el = lane >> 4;          // edge slot 0..3
    int fc = lane & 15;          // feature chunk: feats fc*8 .. fc*8+7
    int n0 = blockIdx.x * NPB;

    float we8[8], be8[8];
#pragma unroll
    for (int q = 0; q < 8; ++q) {
        we8[q] = We[fc * 8 + q];
        be8[q] = be[fc * 8 + q];
    }

    const uint4* hin4 = (const uint4*)hin;   // one 128-feat bf16 row = 16 uint4

    for (int loc = 0; loc < 4; ++loc) {
        int m = wave * 4 + loc;
        int n = n0 + m;
        int r0 = rowptr[n], r1 = rowptr[n + 1];
        float acc[8];
#pragma unroll
        for (int q = 0; q < 8; ++q) acc[q] = 0.f;
#pragma unroll 2
        for (int i = r0 + el; i < r1; i += 4) {
            int2 sa = csr[i];
            int s = sa.x;
            float a = __int_as_float(sa.y);
            uint4 rv = hin4[(size_t)s * 16 + fc];
#pragma unroll
            for (int p = 0; p < 4; ++p) {
                unsigned u = ((const unsigned*)&rv)[p];
                float f0 = __uint_as_float(u << 16);          // low bf16
                float f1 = __uint_as_float(u & 0xffff0000u);  // high bf16
                float m0 = f0 + a * we8[2 * p] + be8[2 * p];
                float m1 = f1 + a * we8[2 * p + 1] + be8[2 * p + 1];
                acc[2 * p]     += m0 > 0.f ? m0 : 0.f;
                acc[2 * p + 1] += m1 > 0.f ? m1 : 0.f;
            }
        }
        // combine the 4 edge slots (lanes l, l^16, l^32 share fc)
#pragma unroll
        for (int q = 0; q < 8; ++q) {
            acc[q] += __shfl_xor(acc[q], 16, 64);
            acc[q] += __shfl_xor(acc[q], 32, 64);
        }
        if (el == 0) {
            uint4 sv = hin4[(size_t)n * 16 + fc];
            unsigned short pk[8];
#pragma unroll
            for (int p = 0; p < 4; ++p) {
                unsigned u = ((const unsigned*)&sv)[p];
                float v0 = acc[2 * p]     + __uint_as_float(u << 16);
                float v1 = acc[2 * p + 1] + __uint_as_float(u & 0xffff0000u);
                bf16 h0 = __float2bfloat16(v0);
                bf16 h1 = __float2bfloat16(v1);
                pk[2 * p]     = *(unsigned short*)&h0;
                pk[2 * p + 1] = *(unsigned short*)&h1;
            }
            *(uint4*)&tl[m][fc * 8] = *(const uint4*)pk;   // one ds_write_b128, conflict-free
        }
    }
    __syncthreads();

    // MFMA node-update: out[m][j] = relu(b[j] + sum_k t[m][k] * W[k][j])
    // wave handles j-tiles jt0=2*wave, jt1=2*wave+1 (all 16 rows).
    int c = lane & 15;           // A row / D col
    int kq = lane >> 4;          // k-chunk selector
    int jt0 = wave * 2, jt1 = jt0 + 1;
    f32x4 d0 = {0.f, 0.f, 0.f, 0.f}, d1 = {0.f, 0.f, 0.f, 0.f};
    const short8* wp = (const short8*)Wp;
#pragma unroll
    for (int kk = 0; kk < 4; ++kk) {
        short8 a  = *(const short8*)&tl[c][kk * 32 + kq * 8];
        short8 b0 = wp[(jt0 * 4 + kk) * 64 + lane];
        short8 b1 = wp[(jt1 * 4 + kk) * 64 + lane];
        d0 = __builtin_amdgcn_mfma_f32_16x16x32_bf16(a, b0, d0, 0, 0, 0);
        d1 = __builtin_amdgcn_mfma_f32_16x16x32_bf16(a, b1, d1, 0, 0, 0);
    }
    float bv0 = b[jt0 * 16 + c];
    float bv1 = b[jt1 * 16 + c];
#pragma unroll
    for (int i = 0; i < 4; ++i) {
        int m = kq * 4 + i;
        size_t base = (size_t)(n0 + m) * HID;
        float v0 = d0[i] + bv0;
        float v1 = d1[i] + bv1;
        hout[base + jt0 * 16 + c] = __float2bfloat16(v0 > 0.f ? v0 : 0.f);
        hout[base + jt1 * 16 + c] = __float2bfloat16(v1 > 0.f ? v1 : 0.f);
    }
}

// ---------------- Pooling + head ----------------

__global__ void pool_kernel(const bf16* __restrict__ h, const int* __restrict__ batch,
                            float* __restrict__ pool, float* __restrict__ cnt) {
    int n0 = blockIdx.x * 64;
    int j = threadIdx.x;
    int nend = n0 + 64;
    if (nend > N_NODES) nend = N_NODES;
    if (n0 >= N_NODES) return;
    float sum = 0.f;
    int curg = batch[n0];
    int runstart = n0;
    for (int n = n0; n < nend; ++n) {
        int g = batch[n];
        if (g != curg) {
            atomicAdd(&pool[curg * HID + j], sum);
            if (j == 0) atomicAdd(&cnt[curg], (float)(n - runstart));
            sum = 0.f;
            curg = g;
            runstart = n;
        }
        sum += __bfloat162float(h[(size_t)n * HID + j]);
    }
    atomicAdd(&pool[curg * HID + j], sum);
    if (j == 0) atomicAdd(&cnt[curg], (float)(nend - runstart));
}

__global__ void final_kernel(const float* __restrict__ pool, const float* __restrict__ cnt,
                             const float* __restrict__ Wlin, const float* __restrict__ blin,
                             float* __restrict__ out) {
    int idx = threadIdx.x;
    if (idx >= N_GRAPHS * N_CLASS) return;
    int g = idx / N_CLASS, c = idx % N_CLASS;
    float invc = 1.f / fmaxf(cnt[g], 1.f);
    float acc = blin[c];
    for (int j = 0; j < HID; ++j) acc += pool[g * HID + j] * invc * Wlin[j * N_CLASS + c];
    out[idx] = acc;
}

extern "C" void kernel_launch(void* const* d_in, const int* in_sizes, int n_in,
                              void* d_out, int out_size, void* d_ws, size_t ws_size,
                              hipStream_t stream) {
    const float* x    = (const float*)d_in[0];
    const int*   ei   = (const int*)d_in[1];
    const float* ea   = (const float*)d_in[2];
    const int*   batch= (const int*)d_in[3];
    const float* We1  = (const float*)d_in[4];
    const float* be1  = (const float*)d_in[5];
    const float* W1   = (const float*)d_in[6];
    const float* b1   = (const float*)d_in[7];
    const float* We2  = (const float*)d_in[8];
    const float* be2  = (const float*)d_in[9];
    const float* W2   = (const float*)d_in[10];
    const float* b2   = (const float*)d_in[11];
    const float* We3  = (const float*)d_in[12];
    const float* be3  = (const float*)d_in[13];
    const float* W3   = (const float*)d_in[14];
    const float* b3   = (const float*)d_in[15];
    const float* Wlin = (const float*)d_in[16];
    const float* blin = (const float*)d_in[17];

    const int* src = ei;
    const int* dst = ei + N_EDGES;

    // workspace layout (csr first: 16B-aligned at base; Wp before A keeps 16B alignment)
    char* w = (char*)d_ws;
    int2*  csr    = (int2*)w;                    w += sizeof(int2) * (size_t)N_EDGES;   // 12.8 MB
    bf16*  Wp2    = (bf16*)w;                    w += sizeof(bf16) * 8 * 4 * 64 * 8;    // 32 KB
    bf16*  Wp3    = (bf16*)w;                    w += sizeof(bf16) * 8 * 4 * 64 * 8;    // 32 KB
    bf16*  A      = (bf16*)w;                    w += sizeof(bf16) * (size_t)N_NODES * HID;
    bf16*  B      = (bf16*)w;                    w += sizeof(bf16) * (size_t)N_NODES * HID;
    float* agg1   = (float*)w;                   w += sizeof(float) * (size_t)N_NODES * N_FEAT;
    float* pool   = (float*)w;                   w += sizeof(float) * N_GRAPHS * HID;
    float* cnt    = (float*)w;                   w += sizeof(float) * N_GRAPHS;
    int*   rowptr = (int*)w;                     w += sizeof(int) * (N_NODES + 1);
    int*   cursor = (int*)w;                     w += sizeof(int) * N_NODES;
    int*   deg    = (int*)w;                     w += sizeof(int) * N_NODES;
    int*   stmp   = (int*)w;                     w += sizeof(int) * N_NODES;
    int*   bsum   = (int*)w;                     w += sizeof(int) * SCAN_NBLK;
    int*   bcur   = (int*)w;                     w += sizeof(int) * NBKT;

    // Pass A/B temporaries alias A (25.6 MB >= 12.8 + 6.4); A is first written
    // by node_l1, strictly after scatter_local completes on the same stream.
    int2* tmp2 = (int2*)A;
    int*  tmpd = (int*)((char*)A + sizeof(int2) * (size_t)N_EDGES);

    // ---- CSR build + weight pack ----
    hipMemsetAsync(deg, 0, sizeof(int) * N_NODES, stream);
    hipMemsetAsync(pool, 0, sizeof(float) * (N_GRAPHS * HID + N_GRAPHS), stream);
    hist_kernel<<<(N_EDGES + 255) / 256, 256, 0, stream>>>(dst, deg);
    pack_w<<<8, 256, 0, stream>>>(W2, Wp2);
    pack_w<<<8, 256, 0, stream>>>(W3, Wp3);
    scan_phase1<<<SCAN_NBLK, 1024, 0, stream>>>(deg, stmp, bsum);
    scan_phase2<<<1, 128, 0, stream>>>(bsum);
    scan_phase3<<<SCAN_NBLK, 1024, 0, stream>>>(stmp, bsum, rowptr, cursor, bcur);
    partition_kernel<<<(N_EDGES + TILE - 1) / TILE, 256, 0, stream>>>(src, dst, ea, bcur, tmp2, tmpd);
    scatter_local<<<8 * ((NBKT + 7) / 8) * CPB, 256, 0, stream>>>(tmp2, tmpd, rowptr, cursor, csr);

    // ---- Layer 1 ----
    agg_l1<<<N_NODES / 4, 64, 0, stream>>>(x, csr, rowptr, We1, be1, agg1);
    node_l1<<<N_NODES, HID, 0, stream>>>(x, agg1, W1, b1, A);            // A = h1 (bf16)

    // ---- Layer 2: A -> B ----
    hidden_layer<<<N_NODES / NPB, 256, 0, stream>>>(A, csr, rowptr, We2, be2, Wp2, b2, B);

    // ---- Layer 3: B -> A ----
    hidden_layer<<<N_NODES / NPB, 256, 0, stream>>>(B, csr, rowptr, We3, be3, Wp3, b3, A);

    // ---- Pool + head ----
    pool_kernel<<<(N_NODES + 63) / 64, HID, 0, stream>>>(A, batch, pool, cnt);
    final_kernel<<<1, 64, 0, stream>>>(pool, cnt, Wlin, blin, (float*)d_out);
}

// Round 9
// 481.262 us; speedup vs baseline: 1.6542x; 1.0311x over previous
//
#include <hip/hip_runtime.h>
#include <hip/hip_bf16.h>

#define N_NODES 100000
#define N_EDGES 1600000
#define N_FEAT 7
#define HID 128
#define N_CLASS 5
#define N_GRAPHS 8
#define NPB 16  // nodes per block in fused layer kernels (grid 6250, 4 waves x 4 nodes)
#define SCAN_NBLK ((N_NODES + 1023) / 1024)   // 98
#define TLP 136  // padded LDS row (bf16 elems): 272 B stride
#define TLP1 40  // layer-1 padded LDS row (K=32 zero-padded + 8): 80 B stride, 2-way banks
#define NBKT 98        // ceil(N_NODES / 1024) dst-buckets for local scatter
#define BKT_SHIFT 10
#define TILE 4096      // edges per partition block
#define CPB 16         // chunks per bucket in scatter_local

typedef __hip_bfloat16 bf16;
typedef __attribute__((ext_vector_type(8))) short short8;   // 8 bf16 (4 VGPRs)
typedef __attribute__((ext_vector_type(4))) float f32x4;    // MFMA accumulator

// ---------------- CSR build (dst-sorted adjacency) ----------------

__global__ void hist_kernel(const int* __restrict__ dst, int* __restrict__ deg) {
    int e = blockIdx.x * blockDim.x + threadIdx.x;
    if (e < N_EDGES) atomicAdd(&deg[dst[e]], 1);
}

__global__ __launch_bounds__(1024) void scan_phase1(const int* __restrict__ deg,
                                                    int* __restrict__ tmp,
                                                    int* __restrict__ bsum) {
    __shared__ int s[1024];
    int tid = threadIdx.x;
    int i = blockIdx.x * 1024 + tid;
    int v = (i < N_NODES) ? deg[i] : 0;
    s[tid] = v;
    __syncthreads();
    for (int off = 1; off < 1024; off <<= 1) {
        int u = (tid >= off) ? s[tid - off] : 0;
        __syncthreads();
        s[tid] += u;
        __syncthreads();
    }
    if (i < N_NODES) tmp[i] = s[tid] - v;            // exclusive
    if (tid == 1023) bsum[blockIdx.x] = s[1023];
}

__global__ __launch_bounds__(128) void scan_phase2(int* __restrict__ bsum) {
    __shared__ int s[128];
    int tid = threadIdx.x;
    int v = (tid < SCAN_NBLK) ? bsum[tid] : 0;
    s[tid] = v;
    __syncthreads();
    for (int off = 1; off < 128; off <<= 1) {
        int u = (tid >= off) ? s[tid - off] : 0;
        __syncthreads();
        s[tid] += u;
        __syncthreads();
    }
    if (tid < SCAN_NBLK) bsum[tid] = s[tid] - v;
}

__global__ __launch_bounds__(1024) void scan_phase3(const int* __restrict__ tmp,
                                                    const int* __restrict__ bsum,
                                                    int* __restrict__ rowptr,
                                                    int* __restrict__ cursor,
                                                    int* __restrict__ bcur) {
    int i = blockIdx.x * 1024 + threadIdx.x;
    if (i < N_NODES) {
        int r = tmp[i] + bsum[blockIdx.x];
        rowptr[i] = r;
        cursor[i] = r;
        if ((i & 1023) == 0) bcur[i >> BKT_SHIFT] = r;   // bucket write cursors for partition
    }
    if (i == 0) rowptr[N_NODES] = N_EDGES;
}

// ---- Pass A: LDS counting-sort each edge tile by dst-bucket, write bucket-major ----
__global__ __launch_bounds__(256) void partition_kernel(
        const int* __restrict__ src, const int* __restrict__ dst,
        const float* __restrict__ ea, int* __restrict__ bcur,
        int2* __restrict__ tmp2, int* __restrict__ tmpd) {
    __shared__ int lsrc[TILE], lea[TILE], ldst[TILE];   // 48 KB
    __shared__ int cnt[NBKT], gbase[NBKT];
    __shared__ int off[128];
    int tid = threadIdx.x;
    int e0 = blockIdx.x * TILE;
    int nedge = N_EDGES - e0; if (nedge > TILE) nedge = TILE;

    for (int bkt = tid; bkt < NBKT; bkt += 256) cnt[bkt] = 0;
    __syncthreads();
    for (int t = tid; t < nedge; t += 256)
        atomicAdd(&cnt[dst[e0 + t] >> BKT_SHIFT], 1);
    __syncthreads();
    if (tid < 128) off[tid] = (tid < NBKT) ? cnt[tid] : 0;
    __syncthreads();
    for (int o = 1; o < 128; o <<= 1) {                  // Hillis-Steele inclusive scan
        int u = 0;
        if (tid < 128 && tid >= o) u = off[tid - o];
        __syncthreads();
        if (tid < 128) off[tid] += u;
        __syncthreads();
    }
    if (tid < NBKT) {
        off[tid] -= cnt[tid];                            // inclusive -> exclusive
        gbase[tid] = atomicAdd(&bcur[tid], cnt[tid]);    // reserve global bucket range
    }
    __syncthreads();
    if (tid < NBKT) cnt[tid] = 0;                        // reuse as rank counter
    __syncthreads();
    for (int t = tid; t < nedge; t += 256) {
        int d = dst[e0 + t];
        int bkt = d >> BKT_SHIFT;
        int sp = off[bkt] + atomicAdd(&cnt[bkt], 1);     // sorted slot in tile
        lsrc[sp] = src[e0 + t];
        lea[sp] = __float_as_int(ea[e0 + t]);
        ldst[sp] = d;
    }
    __syncthreads();
    for (int t = tid; t < nedge; t += 256) {             // bucket-grouped coalesced writeout
        int d = ldst[t];
        int bkt = d >> BKT_SHIFT;
        int gi = gbase[bkt] + (t - off[bkt]);
        tmp2[gi] = make_int2(lsrc[t], lea[t]);
        tmpd[gi] = d;
    }
}

// ---- Pass B: scatter within bucket, bucket pinned to one XCD (blockIdx%8) ----
__global__ __launch_bounds__(256) void scatter_local(
        const int2* __restrict__ tmp2, const int* __restrict__ tmpd,
        const int* __restrict__ rowptr, int* __restrict__ cursor,
        int2* __restrict__ csr) {
    int bid = blockIdx.x;
    int xcd = bid & 7;
    int grp = bid >> 3;
    int b = (grp / CPB) * 8 + xcd;       // bucket: all its chunks share blockIdx%8
    int c = grp % CPB;                    // chunk within bucket
    if (b >= NBKT) return;
    int r0 = rowptr[b << BKT_SHIFT];
    int nb1 = (b + 1) << BKT_SHIFT; if (nb1 > N_NODES) nb1 = N_NODES;
    int r1 = rowptr[nb1];
    int count = r1 - r0;
    int per = (count + CPB - 1) / CPB;
    int s = r0 + c * per;
    int e = s + per; if (e > r1) e = r1;
    for (int i = s + threadIdx.x; i < e; i += 256) {
        int d = tmpd[i];
        int p = atomicAdd(&cursor[d], 1);
        csr[p] = tmp2[i];
    }
}

// ---------------- W pre-pack into MFMA B-fragment order (bf16) ----------------
// B-frag for mfma_f32_16x16x32_bf16: lane l holds B[k=(l>>4)*8+q][col=l&15].

__global__ void pack_w(const float* __restrict__ W, bf16* __restrict__ Wp) {
    int t = blockIdx.x * blockDim.x + threadIdx.x;   // 0..2047
    if (t >= 2048) return;
    int l = t & 63;
    int kk = (t >> 6) & 3;
    int jt = t >> 8;
    int kbase = kk * 32 + (l >> 4) * 8;
    int j = jt * 16 + (l & 15);
#pragma unroll
    for (int q = 0; q < 8; ++q)
        Wp[t * 8 + q] = __float2bfloat16(W[(kbase + q) * HID + j]);
}

// Layer-1 W pack: K=7 zero-padded to 32. Wp1[(jt*64+l)*8+q] = W1[k][j] (k<7) else 0.
__global__ void pack_w1(const float* __restrict__ W, bf16* __restrict__ Wp) {
    int t = blockIdx.x * blockDim.x + threadIdx.x;   // 0..511
    if (t >= 512) return;
    int l = t & 63;
    int jt = t >> 6;
    int j = jt * 16 + (l & 15);
#pragma unroll
    for (int q = 0; q < 8; ++q) {
        int k = (l >> 4) * 8 + q;
        Wp[t * 8 + q] = __float2bfloat16(k < N_FEAT ? W[k * HID + j] : 0.f);
    }
}

// ---------------- Fused layer 1: gather(x, in=7) + MFMA(7x128, K zero-padded) ----------------
// Replaces agg_l1 + node_l1: kills agg1 fp32 roundtrip (5.6 MB) and a 100k-block launch.
__global__ __launch_bounds__(256) void layer1_fused(
        const float* __restrict__ x, const int2* __restrict__ csr,
        const int* __restrict__ rowptr, const float* __restrict__ We,
        const float* __restrict__ be, const bf16* __restrict__ Wp1,
        const float* __restrict__ b, bf16* __restrict__ hout) {
    __shared__ __align__(16) unsigned short tl[NPB][TLP1];   // 1.28 KB
    int tid = threadIdx.x;
    int wave = tid >> 6;
    int lane = tid & 63;
    int sub = lane >> 4;
    int l = lane & 15;
    int n0 = blockIdx.x * NPB;

    for (int i = tid; i < NPB * TLP1; i += 256) ((unsigned short*)tl)[i] = 0;

    float we[N_FEAT], bee[N_FEAT], p[N_FEAT];
#pragma unroll
    for (int k = 0; k < N_FEAT; ++k) { we[k] = We[k]; bee[k] = be[k]; p[k] = 0.f; }
    __syncthreads();   // zero-init visible before lane-0 t-writes

    int m = wave * 4 + sub;
    int n = n0 + m;
    int r0 = rowptr[n], r1 = rowptr[n + 1];
    for (int i = r0 + l; i < r1; i += 16) {
        int2 sa = csr[i];
        int s = sa.x;
        float a = __int_as_float(sa.y);
#pragma unroll
        for (int k = 0; k < N_FEAT; ++k) {
            float mm = x[s * N_FEAT + k] + a * we[k] + bee[k];
            p[k] += mm > 0.f ? mm : 0.f;
        }
    }
#pragma unroll
    for (int off = 8; off >= 1; off >>= 1)
#pragma unroll
        for (int k = 0; k < N_FEAT; ++k)
            p[k] += __shfl_xor(p[k], off, 16);
    if (l == 0) {
#pragma unroll
        for (int k = 0; k < N_FEAT; ++k) {
            bf16 hb = __float2bfloat16(p[k] + x[n * N_FEAT + k]);
            tl[m][k] = *(unsigned short*)&hb;
        }
    }
    __syncthreads();

    // MFMA node-update: one k-step (K=32, k>=7 are zeros)
    int c = lane & 15;
    int kq = lane >> 4;
    int jt0 = wave * 2, jt1 = jt0 + 1;
    f32x4 d0 = {0.f, 0.f, 0.f, 0.f}, d1 = {0.f, 0.f, 0.f, 0.f};
    const short8* wp = (const short8*)Wp1;
    short8 aF = *(const short8*)&tl[c][kq * 8];
    short8 b0 = wp[jt0 * 64 + lane];
    short8 b1 = wp[jt1 * 64 + lane];
    d0 = __builtin_amdgcn_mfma_f32_16x16x32_bf16(aF, b0, d0, 0, 0, 0);
    d1 = __builtin_amdgcn_mfma_f32_16x16x32_bf16(aF, b1, d1, 0, 0, 0);
    float bv0 = b[jt0 * 16 + c];
    float bv1 = b[jt1 * 16 + c];
#pragma unroll
    for (int i = 0; i < 4; ++i) {
        int mm = kq * 4 + i;
        size_t base = (size_t)(n0 + mm) * HID;
        float v0 = d0[i] + bv0;
        float v1 = d1[i] + bv1;
        hout[base + jt0 * 16 + c] = __float2bfloat16(v0 > 0.f ? v0 : 0.f);
        hout[base + jt1 * 16 + c] = __float2bfloat16(v1 > 0.f ? v1 : 0.f);
    }
}

// ---------------- Fused hidden layer: gather-aggregate + MFMA node-update ----------------
// v5: round-7 counters (VALU 52%, HBM 35%, occ 62%) -> still partially
// latency-bound. Pair the wave's 4 nodes into 2 interleaved edge loops ->
// 2 independent csr->row dependency chains, 2x loads in flight (+~16 VGPR).
// hout MUST differ from hin.
#define PROC(rv, a, acc)                                                     \
    {                                                                        \
        _Pragma("unroll") for (int p_ = 0; p_ < 4; ++p_) {                   \
            unsigned u = ((const unsigned*)&(rv))[p_];                       \
            float f0 = __uint_as_float(u << 16);                             \
            float f1 = __uint_as_float(u & 0xffff0000u);                     \
            float m0 = f0 + (a) * we8[2 * p_] + be8[2 * p_];                 \
            float m1 = f1 + (a) * we8[2 * p_ + 1] + be8[2 * p_ + 1];         \
            (acc)[2 * p_] += m0 > 0.f ? m0 : 0.f;                            \
            (acc)[2 * p_ + 1] += m1 > 0.f ? m1 : 0.f;                        \
        }                                                                    \
    }

__global__ __launch_bounds__(256) void hidden_layer(
        const bf16* __restrict__ hin, const int2* __restrict__ csr,
        const int* __restrict__ rowptr, const float* __restrict__ We,
        const float* __restrict__ be, const bf16* __restrict__ Wp,
        const float* __restrict__ b, bf16* __restrict__ hout) {
    __shared__ __align__(16) unsigned short tl[NPB][TLP];   // bf16 bits, 4.3 KB
    int tid = threadIdx.x;
    int wave = tid >> 6;
    int lane = tid & 63;
    int el = lane >> 4;          // edge slot 0..3
    int fc = lane & 15;          // feature chunk: feats fc*8 .. fc*8+7
    int n0 = blockIdx.x * NPB;

    float we8[8], be8[8];
#pragma unroll
    for (int q = 0; q < 8; ++q) {
        we8[q] = We[fc * 8 + q];
        be8[q] = be[fc * 8 + q];
    }

    const uint4* hin4 = (const uint4*)hin;   // one 128-feat bf16 row = 16 uint4

    for (int pr = 0; pr < 2; ++pr) {
        int mA = wave * 4 + pr * 2, mB = mA + 1;
        int nA = n0 + mA, nB = n0 + mB;
        int eA = rowptr[nA + 1], eB = rowptr[nB + 1];
        int iA = rowptr[nA] + el, iB = rowptr[nB] + el;
        float accA[8], accB[8];
#pragma unroll
        for (int q = 0; q < 8; ++q) { accA[q] = 0.f; accB[q] = 0.f; }
        while (iA < eA && iB < eB) {           // two independent gather chains
            int2 sa = csr[iA];
            int2 sb = csr[iB];
            float a = __int_as_float(sa.y);
            float bb = __int_as_float(sb.y);
            uint4 rA = hin4[(size_t)sa.x * 16 + fc];
            uint4 rB = hin4[(size_t)sb.x * 16 + fc];
            PROC(rA, a, accA);
            PROC(rB, bb, accB);
            iA += 4; iB += 4;
        }
        for (; iA < eA; iA += 4) {
            int2 sa = csr[iA];
            float a = __int_as_float(sa.y);
            uint4 rA = hin4[(size_t)sa.x * 16 + fc];
            PROC(rA, a, accA);
        }
        for (; iB < eB; iB += 4) {
            int2 sb = csr[iB];
            float bb = __int_as_float(sb.y);
            uint4 rB = hin4[(size_t)sb.x * 16 + fc];
            PROC(rB, bb, accB);
        }
        // combine the 4 edge slots (lanes l, l^16, l^32 share fc)
#pragma unroll
        for (int q = 0; q < 8; ++q) {
            accA[q] += __shfl_xor(accA[q], 16, 64);
            accA[q] += __shfl_xor(accA[q], 32, 64);
            accB[q] += __shfl_xor(accB[q], 16, 64);
            accB[q] += __shfl_xor(accB[q], 32, 64);
        }
        if (el == 0) {
            uint4 svA = hin4[(size_t)nA * 16 + fc];
            uint4 svB = hin4[(size_t)nB * 16 + fc];
            unsigned short pkA[8], pkB[8];
#pragma unroll
            for (int p = 0; p < 4; ++p) {
                unsigned uA = ((const unsigned*)&svA)[p];
                unsigned uB = ((const unsigned*)&svB)[p];
                float vA0 = accA[2 * p]     + __uint_as_float(uA << 16);
                float vA1 = accA[2 * p + 1] + __uint_as_float(uA & 0xffff0000u);
                float vB0 = accB[2 * p]     + __uint_as_float(uB << 16);
                float vB1 = accB[2 * p + 1] + __uint_as_float(uB & 0xffff0000u);
                bf16 hA0 = __float2bfloat16(vA0), hA1 = __float2bfloat16(vA1);
                bf16 hB0 = __float2bfloat16(vB0), hB1 = __float2bfloat16(vB1);
                pkA[2 * p] = *(unsigned short*)&hA0; pkA[2 * p + 1] = *(unsigned short*)&hA1;
                pkB[2 * p] = *(unsigned short*)&hB0; pkB[2 * p + 1] = *(unsigned short*)&hB1;
            }
            *(uint4*)&tl[mA][fc * 8] = *(const uint4*)pkA;
            *(uint4*)&tl[mB][fc * 8] = *(const uint4*)pkB;
        }
    }
    __syncthreads();

    // MFMA node-update: out[m][j] = relu(b[j] + sum_k t[m][k] * W[k][j])
    // Verified mapping (m89): A lane l: row=l&15, k=(l>>4)*8+q;
    //                         B lane l: col=l&15, k=(l>>4)*8+q;
    //                         D lane l: col=l&15, row=(l>>4)*4+reg.
    int c = lane & 15;           // A row / D col
    int kq = lane >> 4;          // k-chunk selector
    int jt0 = wave * 2, jt1 = jt0 + 1;
    f32x4 d0 = {0.f, 0.f, 0.f, 0.f}, d1 = {0.f, 0.f, 0.f, 0.f};
    const short8* wp = (const short8*)Wp;
#pragma unroll
    for (int kk = 0; kk < 4; ++kk) {
        short8 a  = *(const short8*)&tl[c][kk * 32 + kq * 8];
        short8 b0 = wp[(jt0 * 4 + kk) * 64 + lane];
        short8 b1 = wp[(jt1 * 4 + kk) * 64 + lane];
        d0 = __builtin_amdgcn_mfma_f32_16x16x32_bf16(a, b0, d0, 0, 0, 0);
        d1 = __builtin_amdgcn_mfma_f32_16x16x32_bf16(a, b1, d1, 0, 0, 0);
    }
    float bv0 = b[jt0 * 16 + c];
    float bv1 = b[jt1 * 16 + c];
#pragma unroll
    for (int i = 0; i < 4; ++i) {
        int m = kq * 4 + i;
        size_t base = (size_t)(n0 + m) * HID;
        float v0 = d0[i] + bv0;
        float v1 = d1[i] + bv1;
        hout[base + jt0 * 16 + c] = __float2bfloat16(v0 > 0.f ? v0 : 0.f);
        hout[base + jt1 * 16 + c] = __float2bfloat16(v1 > 0.f ? v1 : 0.f);
    }
}

// ---------------- Pooling + head ----------------

__global__ void pool_kernel(const bf16* __restrict__ h, const int* __restrict__ batch,
                            float* __restrict__ pool, float* __restrict__ cnt) {
    int n0 = blockIdx.x * 64;
    int j = threadIdx.x;
    int nend = n0 + 64;
    if (nend > N_NODES) nend = N_NODES;
    if (n0 >= N_NODES) return;
    float sum = 0.f;
    int curg = batch[n0];
    int runstart = n0;
    for (int n = n0; n < nend; ++n) {
        int g = batch[n];
        if (g != curg) {
            atomicAdd(&pool[curg * HID + j], sum);
            if (j == 0) atomicAdd(&cnt[curg], (float)(n - runstart));
            sum = 0.f;
            curg = g;
            runstart = n;
        }
        sum += __bfloat162float(h[(size_t)n * HID + j]);
    }
    atomicAdd(&pool[curg * HID + j], sum);
    if (j == 0) atomicAdd(&cnt[curg], (float)(nend - runstart));
}

__global__ void final_kernel(const float* __restrict__ pool, const float* __restrict__ cnt,
                             const float* __restrict__ Wlin, const float* __restrict__ blin,
                             float* __restrict__ out) {
    int idx = threadIdx.x;
    if (idx >= N_GRAPHS * N_CLASS) return;
    int g = idx / N_CLASS, c = idx % N_CLASS;
    float invc = 1.f / fmaxf(cnt[g], 1.f);
    float acc = blin[c];
    for (int j = 0; j < HID; ++j) acc += pool[g * HID + j] * invc * Wlin[j * N_CLASS + c];
    out[idx] = acc;
}

extern "C" void kernel_launch(void* const* d_in, const int* in_sizes, int n_in,
                              void* d_out, int out_size, void* d_ws, size_t ws_size,
                              hipStream_t stream) {
    const float* x    = (const float*)d_in[0];
    const int*   ei   = (const int*)d_in[1];
    const float* ea   = (const float*)d_in[2];
    const int*   batch= (const int*)d_in[3];
    const float* We1  = (const float*)d_in[4];
    const float* be1  = (const float*)d_in[5];
    const float* W1   = (const float*)d_in[6];
    const float* b1   = (const float*)d_in[7];
    const float* We2  = (const float*)d_in[8];
    const float* be2  = (const float*)d_in[9];
    const float* W2   = (const float*)d_in[10];
    const float* b2   = (const float*)d_in[11];
    const float* We3  = (const float*)d_in[12];
    const float* be3  = (const float*)d_in[13];
    const float* W3   = (const float*)d_in[14];
    const float* b3   = (const float*)d_in[15];
    const float* Wlin = (const float*)d_in[16];
    const float* blin = (const float*)d_in[17];

    const int* src = ei;
    const int* dst = ei + N_EDGES;

    // workspace layout (csr first: 16B-aligned at base)
    char* w = (char*)d_ws;
    int2*  csr    = (int2*)w;                    w += sizeof(int2) * (size_t)N_EDGES;   // 12.8 MB
    bf16*  Wp2    = (bf16*)w;                    w += sizeof(bf16) * 8 * 4 * 64 * 8;    // 32 KB
    bf16*  Wp3    = (bf16*)w;                    w += sizeof(bf16) * 8 * 4 * 64 * 8;    // 32 KB
    bf16*  Wp1    = (bf16*)w;                    w += sizeof(bf16) * 8 * 64 * 8;        // 8 KB
    bf16*  A      = (bf16*)w;                    w += sizeof(bf16) * (size_t)N_NODES * HID;
    bf16*  B      = (bf16*)w;                    w += sizeof(bf16) * (size_t)N_NODES * HID;
    float* pool   = (float*)w;                   w += sizeof(float) * N_GRAPHS * HID;
    float* cnt    = (float*)w;                   w += sizeof(float) * N_GRAPHS;
    int*   rowptr = (int*)w;                     w += sizeof(int) * (N_NODES + 1);
    int*   cursor = (int*)w;                     w += sizeof(int) * N_NODES;
    int*   deg    = (int*)w;                     w += sizeof(int) * N_NODES;
    int*   stmp   = (int*)w;                     w += sizeof(int) * N_NODES;
    int*   bsum   = (int*)w;                     w += sizeof(int) * SCAN_NBLK;
    int*   bcur   = (int*)w;                     w += sizeof(int) * NBKT;

    // Pass A/B temporaries alias A (25.6 MB >= 12.8 + 6.4); A is first written
    // by layer1_fused, strictly after scatter_local completes on the same stream.
    int2* tmp2 = (int2*)A;
    int*  tmpd = (int*)((char*)A + sizeof(int2) * (size_t)N_EDGES);

    // ---- CSR build + weight pack ----
    hipMemsetAsync(deg, 0, sizeof(int) * N_NODES, stream);
    hipMemsetAsync(pool, 0, sizeof(float) * (N_GRAPHS * HID + N_GRAPHS), stream);
    hist_kernel<<<(N_EDGES + 255) / 256, 256, 0, stream>>>(dst, deg);
    pack_w<<<8, 256, 0, stream>>>(W2, Wp2);
    pack_w<<<8, 256, 0, stream>>>(W3, Wp3);
    pack_w1<<<2, 256, 0, stream>>>(W1, Wp1);
    scan_phase1<<<SCAN_NBLK, 1024, 0, stream>>>(deg, stmp, bsum);
    scan_phase2<<<1, 128, 0, stream>>>(bsum);
    scan_phase3<<<SCAN_NBLK, 1024, 0, stream>>>(stmp, bsum, rowptr, cursor, bcur);
    partition_kernel<<<(N_EDGES + TILE - 1) / TILE, 256, 0, stream>>>(src, dst, ea, bcur, tmp2, tmpd);
    scatter_local<<<8 * ((NBKT + 7) / 8) * CPB, 256, 0, stream>>>(tmp2, tmpd, rowptr, cursor, csr);

    // ---- Layer 1 (fused gather + MFMA) ----
    layer1_fused<<<N_NODES / NPB, 256, 0, stream>>>(x, csr, rowptr, We1, be1, Wp1, b1, A);

    // ---- Layer 2: A -> B ----
    hidden_layer<<<N_NODES / NPB, 256, 0, stream>>>(A, csr, rowptr, We2, be2, Wp2, b2, B);

    // ---- Layer 3: B -> A ----
    hidden_layer<<<N_NODES / NPB, 256, 0, stream>>>(B, csr, rowptr, We3, be3, Wp3, b3, A);

    // ---- Pool + head ----
    pool_kernel<<<(N_NODES + 63) / 64, HID, 0, stream>>>(A, batch, pool, cnt);
    final_kernel<<<1, 64, 0, stream>>>(pool, cnt, Wlin, blin, (float*)d_out);
}

// Round 10
// 480.358 us; speedup vs baseline: 1.6573x; 1.0019x over previous
//
#include <hip/hip_runtime.h>
#include <hip/hip_bf16.h>

#define N_NODES 100000
#define N_EDGES 1600000
#define N_FEAT 7
#define HID 128
#define N_CLASS 5
#define N_GRAPHS 8
#define NPB 16  // nodes per block in fused layer kernels (grid 6250, 4 waves x 4 nodes)
#define SCAN_NBLK ((N_NODES + 1023) / 1024)   // 98
#define TLP 136  // padded LDS row (bf16 elems): 272 B stride
#define TLP1 40  // layer-1 padded LDS row (K=32 zero-padded + 8): 80 B stride
#define NBKT 98        // ceil(N_NODES / 1024) dst-buckets for local scatter
#define BKT_SHIFT 10
#define TILE 4096      // edges per partition block
#define CPB 16         // chunks per bucket in scatter_local

typedef __hip_bfloat16 bf16;
typedef __attribute__((ext_vector_type(8))) short short8;   // 8 bf16 (4 VGPRs)
typedef __attribute__((ext_vector_type(4))) float f32x4;    // MFMA accumulator

// ---------------- CSR build (dst-sorted adjacency) ----------------

__global__ void hist_kernel(const int* __restrict__ dst, int* __restrict__ deg) {
    int e = blockIdx.x * blockDim.x + threadIdx.x;
    if (e < N_EDGES) atomicAdd(&deg[dst[e]], 1);
}

__global__ __launch_bounds__(1024) void scan_phase1(const int* __restrict__ deg,
                                                    int* __restrict__ tmp,
                                                    int* __restrict__ bsum) {
    __shared__ int s[1024];
    int tid = threadIdx.x;
    int i = blockIdx.x * 1024 + tid;
    int v = (i < N_NODES) ? deg[i] : 0;
    s[tid] = v;
    __syncthreads();
    for (int off = 1; off < 1024; off <<= 1) {
        int u = (tid >= off) ? s[tid - off] : 0;
        __syncthreads();
        s[tid] += u;
        __syncthreads();
    }
    if (i < N_NODES) tmp[i] = s[tid] - v;            // exclusive
    if (tid == 1023) bsum[blockIdx.x] = s[1023];
}

__global__ __launch_bounds__(128) void scan_phase2(int* __restrict__ bsum) {
    __shared__ int s[128];
    int tid = threadIdx.x;
    int v = (tid < SCAN_NBLK) ? bsum[tid] : 0;
    s[tid] = v;
    __syncthreads();
    for (int off = 1; off < 128; off <<= 1) {
        int u = (tid >= off) ? s[tid - off] : 0;
        __syncthreads();
        s[tid] += u;
        __syncthreads();
    }
    if (tid < SCAN_NBLK) bsum[tid] = s[tid] - v;
}

__global__ __launch_bounds__(1024) void scan_phase3(const int* __restrict__ tmp,
                                                    const int* __restrict__ bsum,
                                                    int* __restrict__ rowptr,
                                                    int* __restrict__ cursor,
                                                    int* __restrict__ bcur) {
    int i = blockIdx.x * 1024 + threadIdx.x;
    if (i < N_NODES) {
        int r = tmp[i] + bsum[blockIdx.x];
        rowptr[i] = r;
        cursor[i] = r;
        if ((i & 1023) == 0) bcur[i >> BKT_SHIFT] = r;   // bucket write cursors for partition
    }
    if (i == 0) rowptr[N_NODES] = N_EDGES;
}

// ---- Pass A: LDS counting-sort each edge tile by dst-bucket, write bucket-major ----
__global__ __launch_bounds__(256) void partition_kernel(
        const int* __restrict__ src, const int* __restrict__ dst,
        const float* __restrict__ ea, int* __restrict__ bcur,
        int2* __restrict__ tmp2, int* __restrict__ tmpd) {
    __shared__ int lsrc[TILE], lea[TILE], ldst[TILE];   // 48 KB
    __shared__ int cnt[NBKT], gbase[NBKT];
    __shared__ int off[128];
    int tid = threadIdx.x;
    int e0 = blockIdx.x * TILE;
    int nedge = N_EDGES - e0; if (nedge > TILE) nedge = TILE;

    for (int bkt = tid; bkt < NBKT; bkt += 256) cnt[bkt] = 0;
    __syncthreads();
    for (int t = tid; t < nedge; t += 256)
        atomicAdd(&cnt[dst[e0 + t] >> BKT_SHIFT], 1);
    __syncthreads();
    if (tid < 128) off[tid] = (tid < NBKT) ? cnt[tid] : 0;
    __syncthreads();
    for (int o = 1; o < 128; o <<= 1) {                  // Hillis-Steele inclusive scan
        int u = 0;
        if (tid < 128 && tid >= o) u = off[tid - o];
        __syncthreads();
        if (tid < 128) off[tid] += u;
        __syncthreads();
    }
    if (tid < NBKT) {
        off[tid] -= cnt[tid];                            // inclusive -> exclusive
        gbase[tid] = atomicAdd(&bcur[tid], cnt[tid]);    // reserve global bucket range
    }
    __syncthreads();
    if (tid < NBKT) cnt[tid] = 0;                        // reuse as rank counter
    __syncthreads();
    for (int t = tid; t < nedge; t += 256) {
        int d = dst[e0 + t];
        int bkt = d >> BKT_SHIFT;
        int sp = off[bkt] + atomicAdd(&cnt[bkt], 1);     // sorted slot in tile
        lsrc[sp] = src[e0 + t];
        lea[sp] = __float_as_int(ea[e0 + t]);
        ldst[sp] = d;
    }
    __syncthreads();
    for (int t = tid; t < nedge; t += 256) {             // bucket-grouped coalesced writeout
        int d = ldst[t];
        int bkt = d >> BKT_SHIFT;
        int gi = gbase[bkt] + (t - off[bkt]);
        tmp2[gi] = make_int2(lsrc[t], lea[t]);
        tmpd[gi] = d;
    }
}

// ---- Pass B: scatter within bucket, bucket pinned to one XCD (blockIdx%8) ----
__global__ __launch_bounds__(256) void scatter_local(
        const int2* __restrict__ tmp2, const int* __restrict__ tmpd,
        const int* __restrict__ rowptr, int* __restrict__ cursor,
        int2* __restrict__ csr) {
    int bid = blockIdx.x;
    int xcd = bid & 7;
    int grp = bid >> 3;
    int b = (grp / CPB) * 8 + xcd;       // bucket: all its chunks share blockIdx%8
    int c = grp % CPB;                    // chunk within bucket
    if (b >= NBKT) return;
    int r0 = rowptr[b << BKT_SHIFT];
    int nb1 = (b + 1) << BKT_SHIFT; if (nb1 > N_NODES) nb1 = N_NODES;
    int r1 = rowptr[nb1];
    int count = r1 - r0;
    int per = (count + CPB - 1) / CPB;
    int s = r0 + c * per;
    int e = s + per; if (e > r1) e = r1;
    for (int i = s + threadIdx.x; i < e; i += 256) {
        int d = tmpd[i];
        int p = atomicAdd(&cursor[d], 1);
        csr[p] = tmp2[i];
    }
}

// ---------------- W pre-pack into MFMA B-fragment order (bf16) ----------------
// B-frag for mfma_f32_16x16x32_bf16: lane l holds B[k=(l>>4)*8+q][col=l&15].

__global__ void pack_w(const float* __restrict__ W, bf16* __restrict__ Wp) {
    int t = blockIdx.x * blockDim.x + threadIdx.x;   // 0..2047
    if (t >= 2048) return;
    int l = t & 63;
    int kk = (t >> 6) & 3;
    int jt = t >> 8;
    int kbase = kk * 32 + (l >> 4) * 8;
    int j = jt * 16 + (l & 15);
#pragma unroll
    for (int q = 0; q < 8; ++q)
        Wp[t * 8 + q] = __float2bfloat16(W[(kbase + q) * HID + j]);
}

// Layer-1 W pack: K=7 zero-padded to 32. Wp1[(jt*64+l)*8+q] = W1[k][j] (k<7) else 0.
__global__ void pack_w1(const float* __restrict__ W, bf16* __restrict__ Wp) {
    int t = blockIdx.x * blockDim.x + threadIdx.x;   // 0..511
    if (t >= 512) return;
    int l = t & 63;
    int jt = t >> 6;
    int j = jt * 16 + (l & 15);
#pragma unroll
    for (int q = 0; q < 8; ++q) {
        int k = (l >> 4) * 8 + q;
        Wp[t * 8 + q] = __float2bfloat16(k < N_FEAT ? W[k * HID + j] : 0.f);
    }
}

// x pre-pack: fp32 [N][7] -> bf16 [N][8] (16 B rows, 1.6 MB: L2-resident).
// v6: layer-1 gather then issues ONE dwordx4 per edge instead of 7 scalar loads.
__global__ void pack_x(const float* __restrict__ x, bf16* __restrict__ xp) {
    int n = blockIdx.x * blockDim.x + threadIdx.x;
    if (n >= N_NODES) return;
    unsigned short pk[8];
#pragma unroll
    for (int k = 0; k < N_FEAT; ++k) {
        bf16 h = __float2bfloat16(x[n * N_FEAT + k]);
        pk[k] = *(unsigned short*)&h;
    }
    pk[7] = 0;
    *(uint4*)&xp[(size_t)n * 8] = *(const uint4*)pk;
}

// ---------------- Fused layer 1: gather(xp, in=7) + MFMA(7x128, K zero-padded) ----------------
__global__ __launch_bounds__(256) void layer1_fused(
        const bf16* __restrict__ xp, const int2* __restrict__ csr,
        const int* __restrict__ rowptr, const float* __restrict__ We,
        const float* __restrict__ be, const bf16* __restrict__ Wp1,
        const float* __restrict__ b, bf16* __restrict__ hout) {
    __shared__ __align__(16) unsigned short tl[NPB][TLP1];   // 1.28 KB
    int tid = threadIdx.x;
    int wave = tid >> 6;
    int lane = tid & 63;
    int sub = lane >> 4;
    int l = lane & 15;
    int n0 = blockIdx.x * NPB;

    for (int i = tid; i < NPB * TLP1; i += 256) ((unsigned short*)tl)[i] = 0;

    float we[N_FEAT], bee[N_FEAT], p[N_FEAT];
#pragma unroll
    for (int k = 0; k < N_FEAT; ++k) { we[k] = We[k]; bee[k] = be[k]; p[k] = 0.f; }
    __syncthreads();   // zero-init visible before lane-0 t-writes

    const uint4* xp4 = (const uint4*)xp;
    int m = wave * 4 + sub;
    int n = n0 + m;
    int r0 = rowptr[n], r1 = rowptr[n + 1];
    for (int i = r0 + l; i < r1; i += 16) {
        int2 sa = csr[i];
        float a = __int_as_float(sa.y);
        uint4 rv = xp4[sa.x];                        // whole 7-feat row, one load
#pragma unroll
        for (int p_ = 0; p_ < 4; ++p_) {
            unsigned u = ((const unsigned*)&rv)[p_];
            float f0 = __uint_as_float(u << 16);
            float m0 = f0 + a * we[2 * p_] + bee[2 * p_];
            p[2 * p_] += m0 > 0.f ? m0 : 0.f;
            if (2 * p_ + 1 < N_FEAT) {
                float f1 = __uint_as_float(u & 0xffff0000u);
                float m1 = f1 + a * we[2 * p_ + 1] + bee[2 * p_ + 1];
                p[2 * p_ + 1] += m1 > 0.f ? m1 : 0.f;
            }
        }
    }
#pragma unroll
    for (int off = 8; off >= 1; off >>= 1)
#pragma unroll
        for (int k = 0; k < N_FEAT; ++k)
            p[k] += __shfl_xor(p[k], off, 16);
    if (l == 0) {
        uint4 sv = xp4[n];
#pragma unroll
        for (int k = 0; k < N_FEAT; ++k) {
            unsigned u = ((const unsigned*)&sv)[k >> 1];
            float fs = __uint_as_float((k & 1) ? (u & 0xffff0000u) : (u << 16));
            bf16 hb = __float2bfloat16(p[k] + fs);
            tl[m][k] = *(unsigned short*)&hb;
        }
    }
    __syncthreads();

    // MFMA node-update: one k-step (K=32, k>=7 are zeros)
    // Verified mapping (m89): A lane l: row=l&15, k=(l>>4)*8+q;
    //                         B lane l: col=l&15, k=(l>>4)*8+q;
    //                         D lane l: col=l&15, row=(l>>4)*4+reg.
    int c = lane & 15;
    int kq = lane >> 4;
    int jt0 = wave * 2, jt1 = jt0 + 1;
    f32x4 d0 = {0.f, 0.f, 0.f, 0.f}, d1 = {0.f, 0.f, 0.f, 0.f};
    const short8* wp = (const short8*)Wp1;
    short8 aF = *(const short8*)&tl[c][kq * 8];
    short8 b0 = wp[jt0 * 64 + lane];
    short8 b1 = wp[jt1 * 64 + lane];
    d0 = __builtin_amdgcn_mfma_f32_16x16x32_bf16(aF, b0, d0, 0, 0, 0);
    d1 = __builtin_amdgcn_mfma_f32_16x16x32_bf16(aF, b1, d1, 0, 0, 0);
    float bv0 = b[jt0 * 16 + c];
    float bv1 = b[jt1 * 16 + c];
#pragma unroll
    for (int i = 0; i < 4; ++i) {
        int mm = kq * 4 + i;
        size_t base = (size_t)(n0 + mm) * HID;
        float v0 = d0[i] + bv0;
        float v1 = d1[i] + bv1;
        hout[base + jt0 * 16 + c] = __float2bfloat16(v0 > 0.f ? v0 : 0.f);
        hout[base + jt1 * 16 + c] = __float2bfloat16(v1 > 0.f ? v1 : 0.f);
    }
}

// ---------------- Fused hidden layer: gather-aggregate + MFMA node-update ----------------
// v6: reverted to round-7 sequential gather (paired chains regressed: 78.5->81 us,
// VGPR 36->40, occ 62->55 -- gather is transaction-plateau-bound, not chain-bound).
// hout MUST differ from hin.
__global__ __launch_bounds__(256) void hidden_layer(
        const bf16* __restrict__ hin, const int2* __restrict__ csr,
        const int* __restrict__ rowptr, const float* __restrict__ We,
        const float* __restrict__ be, const bf16* __restrict__ Wp,
        const float* __restrict__ b, bf16* __restrict__ hout) {
    __shared__ __align__(16) unsigned short tl[NPB][TLP];   // bf16 bits, 4.3 KB
    int tid = threadIdx.x;
    int wave = tid >> 6;
    int lane = tid & 63;
    int el = lane >> 4;          // edge slot 0..3
    int fc = lane & 15;          // feature chunk: feats fc*8 .. fc*8+7
    int n0 = blockIdx.x * NPB;

    float we8[8], be8[8];
#pragma unroll
    for (int q = 0; q < 8; ++q) {
        we8[q] = We[fc * 8 + q];
        be8[q] = be[fc * 8 + q];
    }

    const uint4* hin4 = (const uint4*)hin;   // one 128-feat bf16 row = 16 uint4

    for (int loc = 0; loc < 4; ++loc) {
        int m = wave * 4 + loc;
        int n = n0 + m;
        int r0 = rowptr[n], r1 = rowptr[n + 1];
        float acc[8];
#pragma unroll
        for (int q = 0; q < 8; ++q) acc[q] = 0.f;
#pragma unroll 2
        for (int i = r0 + el; i < r1; i += 4) {
            int2 sa = csr[i];
            int s = sa.x;
            float a = __int_as_float(sa.y);
            uint4 rv = hin4[(size_t)s * 16 + fc];
#pragma unroll
            for (int p = 0; p < 4; ++p) {
                unsigned u = ((const unsigned*)&rv)[p];
                float f0 = __uint_as_float(u << 16);          // low bf16
                float f1 = __uint_as_float(u & 0xffff0000u);  // high bf16
                float m0 = f0 + a * we8[2 * p] + be8[2 * p];
                float m1 = f1 + a * we8[2 * p + 1] + be8[2 * p + 1];
                acc[2 * p]     += m0 > 0.f ? m0 : 0.f;
                acc[2 * p + 1] += m1 > 0.f ? m1 : 0.f;
            }
        }
        // combine the 4 edge slots (lanes l, l^16, l^32 share fc)
#pragma unroll
        for (int q = 0; q < 8; ++q) {
            acc[q] += __shfl_xor(acc[q], 16, 64);
            acc[q] += __shfl_xor(acc[q], 32, 64);
        }
        if (el == 0) {
            uint4 sv = hin4[(size_t)n * 16 + fc];
            unsigned short pk[8];
#pragma unroll
            for (int p = 0; p < 4; ++p) {
                unsigned u = ((const unsigned*)&sv)[p];
                float v0 = acc[2 * p]     + __uint_as_float(u << 16);
                float v1 = acc[2 * p + 1] + __uint_as_float(u & 0xffff0000u);
                bf16 h0 = __float2bfloat16(v0);
                bf16 h1 = __float2bfloat16(v1);
                pk[2 * p]     = *(unsigned short*)&h0;
                pk[2 * p + 1] = *(unsigned short*)&h1;
            }
            *(uint4*)&tl[m][fc * 8] = *(const uint4*)pk;   // one ds_write_b128, conflict-free
        }
    }
    __syncthreads();

    // MFMA node-update: out[m][j] = relu(b[j] + sum_k t[m][k] * W[k][j])
    int c = lane & 15;           // A row / D col
    int kq = lane >> 4;          // k-chunk selector
    int jt0 = wave * 2, jt1 = jt0 + 1;
    f32x4 d0 = {0.f, 0.f, 0.f, 0.f}, d1 = {0.f, 0.f, 0.f, 0.f};
    const short8* wp = (const short8*)Wp;
#pragma unroll
    for (int kk = 0; kk < 4; ++kk) {
        short8 a  = *(const short8*)&tl[c][kk * 32 + kq * 8];
        short8 b0 = wp[(jt0 * 4 + kk) * 64 + lane];
        short8 b1 = wp[(jt1 * 4 + kk) * 64 + lane];
        d0 = __builtin_amdgcn_mfma_f32_16x16x32_bf16(a, b0, d0, 0, 0, 0);
        d1 = __builtin_amdgcn_mfma_f32_16x16x32_bf16(a, b1, d1, 0, 0, 0);
    }
    float bv0 = b[jt0 * 16 + c];
    float bv1 = b[jt1 * 16 + c];
#pragma unroll
    for (int i = 0; i < 4; ++i) {
        int m = kq * 4 + i;
        size_t base = (size_t)(n0 + m) * HID;
        float v0 = d0[i] + bv0;
        float v1 = d1[i] + bv1;
        hout[base + jt0 * 16 + c] = __float2bfloat16(v0 > 0.f ? v0 : 0.f);
        hout[base + jt1 * 16 + c] = __float2bfloat16(v1 > 0.f ? v1 : 0.f);
    }
}

// ---------------- Pooling + head ----------------

__global__ void pool_kernel(const bf16* __restrict__ h, const int* __restrict__ batch,
                            float* __restrict__ pool, float* __restrict__ cnt) {
    int n0 = blockIdx.x * 64;
    int j = threadIdx.x;
    int nend = n0 + 64;
    if (nend > N_NODES) nend = N_NODES;
    if (n0 >= N_NODES) return;
    float sum = 0.f;
    int curg = batch[n0];
    int runstart = n0;
    for (int n = n0; n < nend; ++n) {
        int g = batch[n];
        if (g != curg) {
            atomicAdd(&pool[curg * HID + j], sum);
            if (j == 0) atomicAdd(&cnt[curg], (float)(n - runstart));
            sum = 0.f;
            curg = g;
            runstart = n;
        }
        sum += __bfloat162float(h[(size_t)n * HID + j]);
    }
    atomicAdd(&pool[curg * HID + j], sum);
    if (j == 0) atomicAdd(&cnt[curg], (float)(nend - runstart));
}

__global__ void final_kernel(const float* __restrict__ pool, const float* __restrict__ cnt,
                             const float* __restrict__ Wlin, const float* __restrict__ blin,
                             float* __restrict__ out) {
    int idx = threadIdx.x;
    if (idx >= N_GRAPHS * N_CLASS) return;
    int g = idx / N_CLASS, c = idx % N_CLASS;
    float invc = 1.f / fmaxf(cnt[g], 1.f);
    float acc = blin[c];
    for (int j = 0; j < HID; ++j) acc += pool[g * HID + j] * invc * Wlin[j * N_CLASS + c];
    out[idx] = acc;
}

extern "C" void kernel_launch(void* const* d_in, const int* in_sizes, int n_in,
                              void* d_out, int out_size, void* d_ws, size_t ws_size,
                              hipStream_t stream) {
    const float* x    = (const float*)d_in[0];
    const int*   ei   = (const int*)d_in[1];
    const float* ea   = (const float*)d_in[2];
    const int*   batch= (const int*)d_in[3];
    const float* We1  = (const float*)d_in[4];
    const float* be1  = (const float*)d_in[5];
    const float* W1   = (const float*)d_in[6];
    const float* b1   = (const float*)d_in[7];
    const float* We2  = (const float*)d_in[8];
    const float* be2  = (const float*)d_in[9];
    const float* W2   = (const float*)d_in[10];
    const float* b2   = (const float*)d_in[11];
    const float* We3  = (const float*)d_in[12];
    const float* be3  = (const float*)d_in[13];
    const float* W3   = (const float*)d_in[14];
    const float* b3   = (const float*)d_in[15];
    const float* Wlin = (const float*)d_in[16];
    const float* blin = (const float*)d_in[17];

    const int* src = ei;
    const int* dst = ei + N_EDGES;

    // workspace layout (csr first: 16B-aligned at base)
    char* w = (char*)d_ws;
    int2*  csr    = (int2*)w;                    w += sizeof(int2) * (size_t)N_EDGES;   // 12.8 MB
    bf16*  Wp2    = (bf16*)w;                    w += sizeof(bf16) * 8 * 4 * 64 * 8;    // 32 KB
    bf16*  Wp3    = (bf16*)w;                    w += sizeof(bf16) * 8 * 4 * 64 * 8;    // 32 KB
    bf16*  Wp1    = (bf16*)w;                    w += sizeof(bf16) * 8 * 64 * 8;        // 8 KB
    bf16*  xp     = (bf16*)w;                    w += sizeof(bf16) * (size_t)N_NODES * 8; // 1.6 MB
    bf16*  A      = (bf16*)w;                    w += sizeof(bf16) * (size_t)N_NODES * HID;
    bf16*  B      = (bf16*)w;                    w += sizeof(bf16) * (size_t)N_NODES * HID;
    float* pool   = (float*)w;                   w += sizeof(float) * N_GRAPHS * HID;
    float* cnt    = (float*)w;                   w += sizeof(float) * N_GRAPHS;
    int*   rowptr = (int*)w;                     w += sizeof(int) * (N_NODES + 1);
    int*   cursor = (int*)w;                     w += sizeof(int) * N_NODES;
    int*   deg    = (int*)w;                     w += sizeof(int) * N_NODES;
    int*   stmp   = (int*)w;                     w += sizeof(int) * N_NODES;
    int*   bsum   = (int*)w;                     w += sizeof(int) * SCAN_NBLK;
    int*   bcur   = (int*)w;                     w += sizeof(int) * NBKT;

    // Pass A/B temporaries alias A (25.6 MB >= 12.8 + 6.4); A is first written
    // by layer1_fused, strictly after scatter_local completes on the same stream.
    int2* tmp2 = (int2*)A;
    int*  tmpd = (int*)((char*)A + sizeof(int2) * (size_t)N_EDGES);

    // ---- CSR build + weight/x pack ----
    hipMemsetAsync(deg, 0, sizeof(int) * N_NODES, stream);
    hipMemsetAsync(pool, 0, sizeof(float) * (N_GRAPHS * HID + N_GRAPHS), stream);
    hist_kernel<<<(N_EDGES + 255) / 256, 256, 0, stream>>>(dst, deg);
    pack_w<<<8, 256, 0, stream>>>(W2, Wp2);
    pack_w<<<8, 256, 0, stream>>>(W3, Wp3);
    pack_w1<<<2, 256, 0, stream>>>(W1, Wp1);
    pack_x<<<(N_NODES + 255) / 256, 256, 0, stream>>>(x, xp);
    scan_phase1<<<SCAN_NBLK, 1024, 0, stream>>>(deg, stmp, bsum);
    scan_phase2<<<1, 128, 0, stream>>>(bsum);
    scan_phase3<<<SCAN_NBLK, 1024, 0, stream>>>(stmp, bsum, rowptr, cursor, bcur);
    partition_kernel<<<(N_EDGES + TILE - 1) / TILE, 256, 0, stream>>>(src, dst, ea, bcur, tmp2, tmpd);
    scatter_local<<<8 * ((NBKT + 7) / 8) * CPB, 256, 0, stream>>>(tmp2, tmpd, rowptr, cursor, csr);

    // ---- Layer 1 (fused gather + MFMA, packed x) ----
    layer1_fused<<<N_NODES / NPB, 256, 0, stream>>>(xp, csr, rowptr, We1, be1, Wp1, b1, A);

    // ---- Layer 2: A -> B ----
    hidden_layer<<<N_NODES / NPB, 256, 0, stream>>>(A, csr, rowptr, We2, be2, Wp2, b2, B);

    // ---- Layer 3: B -> A ----
    hidden_layer<<<N_NODES / NPB, 256, 0, stream>>>(B, csr, rowptr, We3, be3, Wp3, b3, A);

    // ---- Pool + head ----
    pool_kernel<<<(N_NODES + 63) / 64, HID, 0, stream>>>(A, batch, pool, cnt);
    final_kernel<<<1, 64, 0, stream>>>(pool, cnt, Wlin, blin, (float*)d_out);
}